// Round 15
// baseline (1508.791 us; speedup 1.0000x reference)
//
#include <hip/hip_runtime.h>

#define BB 16
#define PP 2048
#define NN 32768   // BB*PP
#define KK 16
#define EPSF 1e-5f

// ============================================================
// Wave-parallel top-16 selection (R12 known-good — FROZEN).
// R13's deeper Q-caching spilled (360 MB scratch, 130us) -> this exact form
// (88us, ~4MB, VALUBusy 93%). Do not add live state to this loop without
// checking FETCH/WRITE_SIZE afterwards.
// Slot j on lane `lane` = candidate (j>>2)*256 + (j&3) + lane*4. Tie
// semantics: prefer-left in-lane tree + cross-lane exact min-ci via ballot
// == stable lax.top_k, bit-identical.
// ============================================================
#define REP32(M) M(0) M(1) M(2) M(3) M(4) M(5) M(6) M(7) M(8) M(9) M(10) M(11) \
                 M(12) M(13) M(14) M(15) M(16) M(17) M(18) M(19) M(20) M(21) M(22) \
                 M(23) M(24) M(25) M(26) M(27) M(28) M(29) M(30) M(31)
#define DECLD(j) float D##j;

#define MPS(EO, FO, DA, JA, DB, JB) \
    { bool lt_ = (DB) < (DA); EO = lt_ ? (DB) : (DA); FO = lt_ ? (JB) : (JA); }

#define GTREE(GV, GS, dA,sA, dB,sB, dC,sC, dD,sD, dE,sE, dF,sF, dG,sG, dH,sH) { \
    float p0_, p1_, p2_, p3_, q0_, q1_; int o0_, o1_, o2_, o3_, r0_, r1_; \
    MPS(p0_, o0_, dA, sA, dB, sB) \
    MPS(p1_, o1_, dC, sC, dD, sD) \
    MPS(p2_, o2_, dE, sE, dF, sF) \
    MPS(p3_, o3_, dG, sG, dH, sH) \
    MPS(q0_, r0_, p0_, o0_, p1_, o1_) \
    MPS(q1_, r1_, p2_, o2_, p3_, o3_) \
    MPS(GV, GS, q0_, r0_, q1_, r1_) }

#define GT0 GTREE(G0v,H0v, D0,0,D1,1,D2,2,D3,3,D4,4,D5,5,D6,6,D7,7)
#define GT1 GTREE(G1v,H1v, D8,8,D9,9,D10,10,D11,11,D12,12,D13,13,D14,14,D15,15)
#define GT2 GTREE(G2v,H2v, D16,16,D17,17,D18,18,D19,19,D20,20,D21,21,D22,22,D23,23)
#define GT3 GTREE(G3v,H3v, D24,24,D25,25,D26,26,D27,27,D28,28,D29,29,D30,30,D31,31)

#define INVG0 \
    D0 = (wslot_ == 0) ? 3.4e38f : D0;  D1 = (wslot_ == 1) ? 3.4e38f : D1; \
    D2 = (wslot_ == 2) ? 3.4e38f : D2;  D3 = (wslot_ == 3) ? 3.4e38f : D3; \
    D4 = (wslot_ == 4) ? 3.4e38f : D4;  D5 = (wslot_ == 5) ? 3.4e38f : D5; \
    D6 = (wslot_ == 6) ? 3.4e38f : D6;  D7 = (wslot_ == 7) ? 3.4e38f : D7;
#define INVG1 \
    D8  = (wslot_ == 8)  ? 3.4e38f : D8;  D9  = (wslot_ == 9)  ? 3.4e38f : D9; \
    D10 = (wslot_ == 10) ? 3.4e38f : D10; D11 = (wslot_ == 11) ? 3.4e38f : D11; \
    D12 = (wslot_ == 12) ? 3.4e38f : D12; D13 = (wslot_ == 13) ? 3.4e38f : D13; \
    D14 = (wslot_ == 14) ? 3.4e38f : D14; D15 = (wslot_ == 15) ? 3.4e38f : D15;
#define INVG2 \
    D16 = (wslot_ == 16) ? 3.4e38f : D16; D17 = (wslot_ == 17) ? 3.4e38f : D17; \
    D18 = (wslot_ == 18) ? 3.4e38f : D18; D19 = (wslot_ == 19) ? 3.4e38f : D19; \
    D20 = (wslot_ == 20) ? 3.4e38f : D20; D21 = (wslot_ == 21) ? 3.4e38f : D21; \
    D22 = (wslot_ == 22) ? 3.4e38f : D22; D23 = (wslot_ == 23) ? 3.4e38f : D23;
#define INVG3 \
    D24 = (wslot_ == 24) ? 3.4e38f : D24; D25 = (wslot_ == 25) ? 3.4e38f : D25; \
    D26 = (wslot_ == 26) ? 3.4e38f : D26; D27 = (wslot_ == 27) ? 3.4e38f : D27; \
    D28 = (wslot_ == 28) ? 3.4e38f : D28; D29 = (wslot_ == 29) ? 3.4e38f : D29; \
    D30 = (wslot_ == 30) ? 3.4e38f : D30; D31 = (wslot_ == 31) ? 3.4e38f : D31;

#define TOPK16_BODY(OROW, BASE) { \
    float G0v, G1v, G2v, G3v; int H0v, H1v, H2v, H3v; \
    GT0 GT1 GT2 GT3 \
    int mykeep_ = 0; \
    for (int it_ = 0; it_ < KK; ++it_) { \
        float z_; int y_; \
        { float u0_, u1_; int v0_, v1_; \
          MPS(u0_, v0_, G0v, H0v, G1v, H1v) \
          MPS(u1_, v1_, G2v, H2v, G3v, H3v) \
          MPS(z_, y_, u0_, v0_, u1_, v1_) } \
        float v_ = z_; \
        _Pragma("unroll") \
        for (int off_ = 32; off_; off_ >>= 1) \
            v_ = fminf(v_, __shfl_xor(v_, off_)); \
        const int cil_ = ((y_ >> 2) << 8) + (y_ & 3) + (lane << 2); \
        unsigned long long mk_ = __ballot(z_ == v_); \
        int ci_; \
        if (__popcll(mk_) == 1) { \
            ci_ = __shfl(cil_, (int)(__ffsll((long long)mk_) - 1)); \
        } else { \
            ci_ = 0x7fffffff; \
            unsigned long long m2_ = mk_; \
            while (m2_) { \
                int l2_ = (int)(__ffsll((long long)m2_) - 1); \
                int c2_ = __shfl(cil_, l2_); \
                ci_ = c2_ < ci_ ? c2_ : ci_; \
                m2_ &= m2_ - 1; \
            } \
        } \
        const int wslot_ = ((ci_ >> 8) << 2) | (ci_ & 3); \
        if (lane == ((ci_ & 255) >> 2)) { \
            if (wslot_ < 8)       { INVG0 GT0 } \
            else if (wslot_ < 16) { INVG1 GT1 } \
            else if (wslot_ < 24) { INVG2 GT2 } \
            else                  { INVG3 GT3 } \
        } \
        mykeep_ = (lane == it_) ? ci_ : mykeep_; \
    } \
    if (lane < KK) (OROW)[lane] = (BASE) + mykeep_; \
}

// ============================ 3-D KNN (ONE query per wave, 8 waves/block) ============================
#define KNN3_CHUNK(jj, a0, a1, a2, a3) { \
    float4 cx = px4[jj * 64 + lane]; \
    float4 cy = py4[jj * 64 + lane]; \
    float4 cz = pz4[jj * 64 + lane]; \
    float4 cs = pq4[jj * 64 + lane]; \
    const int c0_ = jj * 256 + lane * 4; \
    D##a0 = sqQ + cs.x - 2.f * (qx * cx.x + qy * cy.x + qz * cz.x); if (c0_ + 0 == q) D##a0 += 1e10f; \
    D##a1 = sqQ + cs.y - 2.f * (qx * cx.y + qy * cy.y + qz * cz.y); if (c0_ + 1 == q) D##a1 += 1e10f; \
    D##a2 = sqQ + cs.z - 2.f * (qx * cx.z + qy * cy.z + qz * cz.z); if (c0_ + 2 == q) D##a2 += 1e10f; \
    D##a3 = sqQ + cs.w - 2.f * (qx * cx.w + qy * cy.w + qz * cz.w); if (c0_ + 3 == q) D##a3 += 1e10f; \
}

__global__ void __launch_bounds__(512, 8) knn3v3_kernel(const float* __restrict__ x,
                                                        int* __restrict__ idx) {
    __shared__ float spx[PP], spy[PP], spz[PP], ssq[PP];
    const int b = blockIdx.y, tid = threadIdx.x;
    const float* xc = x + (size_t)b * PP * 3;
    for (int i = tid; i < PP; i += 512) {
        float a = xc[i * 3 + 0], b2 = xc[i * 3 + 1], c2 = xc[i * 3 + 2];
        spx[i] = a; spy[i] = b2; spz[i] = c2;
        ssq[i] = a * a + b2 * b2 + c2 * c2;
    }
    __syncthreads();
    const int lane = tid & 63, wv = tid >> 6;
    const float4* px4 = (const float4*)spx;
    const float4* py4 = (const float4*)spy;
    const float4* pz4 = (const float4*)spz;
    const float4* pq4 = (const float4*)ssq;
    const int q = blockIdx.x * 8 + wv;
    const float qx = spx[q], qy = spy[q], qz = spz[q], sqQ = ssq[q];
    REP32(DECLD)
    KNN3_CHUNK(0, 0, 1, 2, 3)   KNN3_CHUNK(1, 4, 5, 6, 7)
    KNN3_CHUNK(2, 8, 9, 10, 11) KNN3_CHUNK(3, 12, 13, 14, 15)
    KNN3_CHUNK(4, 16, 17, 18, 19) KNN3_CHUNK(5, 20, 21, 22, 23)
    KNN3_CHUNK(6, 24, 25, 26, 27) KNN3_CHUNK(7, 28, 29, 30, 31)
    int* orow = idx + ((size_t)b * PP + q) * KK;
    TOPK16_BODY(orow, b * PP)
}

// ============================ local covariance -> h0[N,12] ============================
__global__ void cov_kernel(const float* __restrict__ x, const int* __restrict__ idx,
                           float* __restrict__ h0) {
    int p = blockIdx.x * 256 + threadIdx.x;
    if (p >= NN) return;
    const int* ip = idx + (size_t)p * KK;
    float nx[KK], ny[KK], nz[KK];
    float mx = 0.f, my = 0.f, mz = 0.f;
    #pragma unroll
    for (int k = 0; k < KK; ++k) {
        int j = ip[k];
        float a = x[j * 3 + 0], b2 = x[j * 3 + 1], c2 = x[j * 3 + 2];
        nx[k] = a; ny[k] = b2; nz[k] = c2;
        mx += a; my += b2; mz += c2;
    }
    mx *= (1.f / KK); my *= (1.f / KK); mz *= (1.f / KK);
    float cxx = 0, cxy = 0, cxz = 0, cyy = 0, cyz = 0, czz = 0;
    #pragma unroll
    for (int k = 0; k < KK; ++k) {
        float a = nx[k] - mx, b2 = ny[k] - my, c2 = nz[k] - mz;
        cxx += a * a;  cxy += a * b2;  cxz += a * c2;
        cyy += b2 * b2; cyz += b2 * c2; czz += c2 * c2;
    }
    const float s = 1.f / KK;
    float* o = h0 + (size_t)p * 12;
    o[0] = x[p * 3 + 0]; o[1] = x[p * 3 + 1]; o[2] = x[p * 3 + 2];
    o[3] = cxx * s; o[4]  = cxy * s; o[5]  = cxz * s;
    o[6] = cxy * s; o[7]  = cyy * s; o[8]  = cyz * s;
    o[9] = cxz * s; o[10] = cyz * s; o[11] = czz * s;
}

// ============ GEMM (64-tile) + fused BN-stats epilogue (+ optional BN-ReLU on A-load) ============
__global__ void gemm_stats_kernel(const float* __restrict__ A, const float* __restrict__ W,
                                  const float* __restrict__ bias, float* __restrict__ C,
                                  const float* __restrict__ aIn, const float* __restrict__ bIn,
                                  float* __restrict__ ps, float* __restrict__ pss,
                                  int K, int Nc) {
    __shared__ float As[16][68];
    __shared__ float Ws[16][68];
    const int tid = threadIdx.x;
    const int m0 = blockIdx.y * 64, n0 = blockIdx.x * 64;
    const int tx = tid & 15, ty = tid >> 4;
    float acc[4][4] = {};
    for (int k0 = 0; k0 < K; k0 += 16) {
        {
            int kk = tid & 15, mp0 = tid >> 4;
            bool kok = (k0 + kk < K);
            float ai = 1.f, bi = 0.f;
            if (aIn && kok) { ai = aIn[k0 + kk]; bi = bIn[k0 + kk]; }
            #pragma unroll
            for (int i = 0; i < 4; ++i) {
                int mp = mp0 + i * 16;
                float v = 0.f;
                if (kok) {
                    v = A[(size_t)(m0 + mp) * K + k0 + kk];
                    if (aIn) { v = fmaf(v, ai, bi); v = v > 0.f ? v : 0.f; }
                }
                As[kk][mp] = v;
            }
            int nn = tid & 63, kb = tid >> 6;
            #pragma unroll
            for (int i = 0; i < 4; ++i) {
                int kk3 = kb + i * 4;
                float v = 0.f;
                if (k0 + kk3 < K) v = W[(size_t)(k0 + kk3) * Nc + n0 + nn];
                Ws[kk3][nn] = v;
            }
        }
        __syncthreads();
        #pragma unroll
        for (int kk = 0; kk < 16; ++kk) {
            float4 a4 = *(const float4*)&As[kk][ty * 4];
            float4 b4 = *(const float4*)&Ws[kk][tx * 4];
            float av[4] = {a4.x, a4.y, a4.z, a4.w};
            float bv[4] = {b4.x, b4.y, b4.z, b4.w};
            #pragma unroll
            for (int i = 0; i < 4; ++i)
                #pragma unroll
                for (int j = 0; j < 4; ++j)
                    acc[i][j] = fmaf(av[i], bv[j], acc[i][j]);
        }
        __syncthreads();
    }
    float4 bb = *(const float4*)&bias[n0 + tx * 4];
    float bvv[4] = {bb.x, bb.y, bb.z, bb.w};
    float colS[4] = {}, colSS[4] = {};
    #pragma unroll
    for (int i = 0; i < 4; ++i) {
        int m = m0 + ty * 4 + i;
        float r[4];
        #pragma unroll
        for (int j = 0; j < 4; ++j) {
            r[j] = acc[i][j] + bvv[j];
            colS[j] += r[j];
            colSS[j] += r[j] * r[j];
        }
        float4 rr = {r[0], r[1], r[2], r[3]};
        *(float4*)&C[(size_t)m * Nc + n0 + tx * 4] = rr;
    }
    #pragma unroll
    for (int j = 0; j < 4; ++j) { As[ty][tx * 4 + j] = colS[j]; Ws[ty][tx * 4 + j] = colSS[j]; }
    __syncthreads();
    if (tid < 64) {
        float s = 0.f, ss = 0.f;
        #pragma unroll
        for (int t = 0; t < 16; ++t) { s += As[t][tid]; ss += Ws[t][tid]; }
        ps [(size_t)blockIdx.y * Nc + n0 + tid] = s;
        pss[(size_t)blockIdx.y * Nc + n0 + tid] = ss;
    }
}

// ============ GEMM (128-tile, 8x8 acc) + fused BN-stats epilogue ============
__global__ void gemm_stats128_kernel(const float* __restrict__ A, const float* __restrict__ W,
                                     const float* __restrict__ bias, float* __restrict__ C,
                                     float* __restrict__ ps, float* __restrict__ pss,
                                     int K, int Nc) {
    __shared__ float As[16][136];
    __shared__ float Ws[16][136];
    const int tid = threadIdx.x;
    const int m0 = blockIdx.y * 128, n0 = blockIdx.x * 128;
    const int tx = tid & 15, ty = tid >> 4;
    float acc[8][8] = {};
    for (int k0 = 0; k0 < K; k0 += 16) {
        {
            const int kk = tid & 15, r0 = tid >> 4;
            #pragma unroll
            for (int i = 0; i < 8; ++i) {
                int r = r0 + i * 16;
                As[kk][r] = A[(size_t)(m0 + r) * K + k0 + kk];
            }
            const int col = tid & 127, kb = tid >> 7;
            #pragma unroll
            for (int i = 0; i < 8; ++i) {
                int kk3 = kb + i * 2;
                Ws[kk3][col] = W[(size_t)(k0 + kk3) * Nc + n0 + col];
            }
        }
        __syncthreads();
        #pragma unroll
        for (int kk2 = 0; kk2 < 16; ++kk2) {
            float4 a0 = *(const float4*)&As[kk2][ty * 8];
            float4 a1 = *(const float4*)&As[kk2][ty * 8 + 4];
            float4 b0 = *(const float4*)&Ws[kk2][tx * 8];
            float4 b1 = *(const float4*)&Ws[kk2][tx * 8 + 4];
            float av[8] = {a0.x, a0.y, a0.z, a0.w, a1.x, a1.y, a1.z, a1.w};
            float bv[8] = {b0.x, b0.y, b0.z, b0.w, b1.x, b1.y, b1.z, b1.w};
            #pragma unroll
            for (int i = 0; i < 8; ++i)
                #pragma unroll
                for (int j = 0; j < 8; ++j)
                    acc[i][j] = fmaf(av[i], bv[j], acc[i][j]);
        }
        __syncthreads();
    }
    float4 bb0 = *(const float4*)&bias[n0 + tx * 8];
    float4 bb1 = *(const float4*)&bias[n0 + tx * 8 + 4];
    float bvv[8] = {bb0.x, bb0.y, bb0.z, bb0.w, bb1.x, bb1.y, bb1.z, bb1.w};
    float colS[8] = {}, colSS[8] = {};
    #pragma unroll
    for (int i = 0; i < 8; ++i) {
        int m = m0 + ty * 8 + i;
        float r[8];
        #pragma unroll
        for (int j = 0; j < 8; ++j) {
            r[j] = acc[i][j] + bvv[j];
            colS[j] += r[j];
            colSS[j] += r[j] * r[j];
        }
        float4 r0v = {r[0], r[1], r[2], r[3]};
        float4 r1v = {r[4], r[5], r[6], r[7]};
        float* row = &C[(size_t)m * Nc + n0 + tx * 8];
        *(float4*)row = r0v;
        *(float4*)(row + 4) = r1v;
    }
    #pragma unroll
    for (int j = 0; j < 8; ++j) { As[ty][tx * 8 + j] = colS[j]; Ws[ty][tx * 8 + j] = colSS[j]; }
    __syncthreads();
    if (tid < 128) {
        float s = 0.f, ss = 0.f;
        #pragma unroll
        for (int t = 0; t < 16; ++t) { s += As[t][tid]; ss += Ws[t][tid]; }
        ps [(size_t)blockIdx.y * Nc + n0 + tid] = s;
        pss[(size_t)blockIdx.y * Nc + n0 + tid] = ss;
    }
}

// ============ GEMM (128-tile) with FUSED gather-max A + BN-stats epilogue ============
// A[m][k] = max_{j<16} f[idx[m][j]][k] computed on the fly (idx rows cached in
// LDS once per block; f is L2-resident: hA 8MB / hg1 16MB). Replaces the
// gathermax4 kernel + agg buffer round trip (96 MB HBM) for graph layers.
// Max order j=0..15 identical to gathermax4 -> bitwise-same A.
// grid: (Nc/128, NN/128), block 256.
__global__ void gemm_gather_stats128_kernel(const float* __restrict__ f,
                                            const int* __restrict__ idx,
                                            const float* __restrict__ W,
                                            const float* __restrict__ bias,
                                            float* __restrict__ C,
                                            float* __restrict__ ps, float* __restrict__ pss,
                                            int K, int Nc) {
    __shared__ float As[16][136];
    __shared__ float Ws[16][136];
    __shared__ int   sIdx[128][16];
    const int tid = threadIdx.x;
    const int m0 = blockIdx.y * 128, n0 = blockIdx.x * 128;
    const int tx = tid & 15, ty = tid >> 4;
    for (int i = tid; i < 128 * 16; i += 256) {
        int r = i >> 4, j = i & 15;
        sIdx[r][j] = idx[(size_t)(m0 + r) * KK + j];
    }
    __syncthreads();
    float acc[8][8] = {};
    for (int k0 = 0; k0 < K; k0 += 16) {
        {
            const int kk = tid & 15, r0 = tid >> 4;
            #pragma unroll
            for (int i = 0; i < 8; ++i) {
                int r = r0 + i * 16;
                float v = -3.4e38f;
                #pragma unroll
                for (int j = 0; j < 16; ++j)
                    v = fmaxf(v, f[(size_t)sIdx[r][j] * K + k0 + kk]);
                As[kk][r] = v;
            }
            const int col = tid & 127, kb = tid >> 7;
            #pragma unroll
            for (int i = 0; i < 8; ++i) {
                int kk3 = kb + i * 2;
                Ws[kk3][col] = W[(size_t)(k0 + kk3) * Nc + n0 + col];
            }
        }
        __syncthreads();
        #pragma unroll
        for (int kk2 = 0; kk2 < 16; ++kk2) {
            float4 a0 = *(const float4*)&As[kk2][ty * 8];
            float4 a1 = *(const float4*)&As[kk2][ty * 8 + 4];
            float4 b0 = *(const float4*)&Ws[kk2][tx * 8];
            float4 b1 = *(const float4*)&Ws[kk2][tx * 8 + 4];
            float av[8] = {a0.x, a0.y, a0.z, a0.w, a1.x, a1.y, a1.z, a1.w};
            float bv[8] = {b0.x, b0.y, b0.z, b0.w, b1.x, b1.y, b1.z, b1.w};
            #pragma unroll
            for (int i = 0; i < 8; ++i)
                #pragma unroll
                for (int j = 0; j < 8; ++j)
                    acc[i][j] = fmaf(av[i], bv[j], acc[i][j]);
        }
        __syncthreads();
    }
    float4 bb0 = *(const float4*)&bias[n0 + tx * 8];
    float4 bb1 = *(const float4*)&bias[n0 + tx * 8 + 4];
    float bvv[8] = {bb0.x, bb0.y, bb0.z, bb0.w, bb1.x, bb1.y, bb1.z, bb1.w};
    float colS[8] = {}, colSS[8] = {};
    #pragma unroll
    for (int i = 0; i < 8; ++i) {
        int m = m0 + ty * 8 + i;
        float r[8];
        #pragma unroll
        for (int j = 0; j < 8; ++j) {
            r[j] = acc[i][j] + bvv[j];
            colS[j] += r[j];
            colSS[j] += r[j] * r[j];
        }
        float4 r0v = {r[0], r[1], r[2], r[3]};
        float4 r1v = {r[4], r[5], r[6], r[7]};
        float* row = &C[(size_t)m * Nc + n0 + tx * 8];
        *(float4*)row = r0v;
        *(float4*)(row + 4) = r1v;
    }
    #pragma unroll
    for (int j = 0; j < 8; ++j) { As[ty][tx * 8 + j] = colS[j]; Ws[ty][tx * 8 + j] = colSS[j]; }
    __syncthreads();
    if (tid < 128) {
        float s = 0.f, ss = 0.f;
        #pragma unroll
        for (int t = 0; t < 16; ++t) { s += As[t][tid]; ss += Ws[t][tid]; }
        ps [(size_t)blockIdx.y * Nc + n0 + tid] = s;
        pss[(size_t)blockIdx.y * Nc + n0 + tid] = ss;
    }
}

// ============ SYMMETRIC gram, 128x128 tiles, upper triangle + mirrored write ============
__global__ void gram128_sym_kernel(const float* __restrict__ f, float* __restrict__ G,
                                   int D, int b0) {
    __shared__ float As[16][132];
    __shared__ float Bs[16][132];
    int t = blockIdx.x, ti = 0;
    while (t >= 16 - ti) { t -= 16 - ti; ++ti; }
    const int tj = ti + t;                    // ti <= tj
    const int pm0 = ti * 128, qn0 = tj * 128;
    const float* fc = f + (size_t)(b0 + blockIdx.y) * PP * D;
    float* Gb = G + (size_t)blockIdx.y * PP * PP;
    const int tid = threadIdx.x;
    const int tx = tid & 15, ty = tid >> 4;
    float acc[8][8] = {};
    for (int k0 = 0; k0 < D; k0 += 16) {
        const int kk = tid & 15, r0 = tid >> 4;
        #pragma unroll
        for (int i = 0; i < 8; ++i) {
            int r = r0 + i * 16;
            As[kk][r] = fc[(size_t)(pm0 + r) * D + k0 + kk];
            Bs[kk][r] = fc[(size_t)(qn0 + r) * D + k0 + kk];
        }
        __syncthreads();
        #pragma unroll
        for (int kk2 = 0; kk2 < 16; ++kk2) {
            float4 a0 = *(const float4*)&As[kk2][ty * 8];
            float4 a1 = *(const float4*)&As[kk2][ty * 8 + 4];
            float4 b0v = *(const float4*)&Bs[kk2][tx * 8];
            float4 b1v = *(const float4*)&Bs[kk2][tx * 8 + 4];
            float av[8] = {a0.x, a0.y, a0.z, a0.w, a1.x, a1.y, a1.z, a1.w};
            float bv[8] = {b0v.x, b0v.y, b0v.z, b0v.w, b1v.x, b1v.y, b1v.z, b1v.w};
            #pragma unroll
            for (int i = 0; i < 8; ++i)
                #pragma unroll
                for (int j = 0; j < 8; ++j)
                    acc[i][j] = fmaf(av[i], bv[j], acc[i][j]);
        }
        __syncthreads();
    }
    #pragma unroll
    for (int i = 0; i < 8; ++i) {
        float4 r0v = {acc[i][0], acc[i][1], acc[i][2], acc[i][3]};
        float4 r1v = {acc[i][4], acc[i][5], acc[i][6], acc[i][7]};
        float* row = Gb + (size_t)(pm0 + ty * 8 + i) * PP + qn0 + tx * 8;
        *(float4*)row = r0v;
        *(float4*)(row + 4) = r1v;
    }
    if (ti != tj) {
        #pragma unroll
        for (int j = 0; j < 8; ++j) {
            float4 c0 = {acc[0][j], acc[1][j], acc[2][j], acc[3][j]};
            float4 c1 = {acc[4][j], acc[5][j], acc[6][j], acc[7][j]};
            float* row = Gb + (size_t)(qn0 + tx * 8 + j) * PP + pm0 + ty * 8;
            *(float4*)row = c0;
            *(float4*)(row + 4) = c1;
        }
    }
}

// ============ top-16 from full gram rows (wave per query, batch-group G) ============
#define SEL_CHUNK(jj, a0, a1, a2, a3) { \
    float4 g4 = Gr[jj * 64 + lane]; \
    float4 s4 = sq4[jj * 64 + lane]; \
    const int c0_ = jj * 256 + lane * 4; \
    D##a0 = sqQ + s4.x - 2.f * g4.x; if (c0_ + 0 == ql) D##a0 += 1e10f; \
    D##a1 = sqQ + s4.y - 2.f * g4.y; if (c0_ + 1 == ql) D##a1 += 1e10f; \
    D##a2 = sqQ + s4.z - 2.f * g4.z; if (c0_ + 2 == ql) D##a2 += 1e10f; \
    D##a3 = sqQ + s4.w - 2.f * g4.w; if (c0_ + 3 == ql) D##a3 += 1e10f; \
}

// 8 blocks/CU -> 32 waves/CU (8 KB LDS each).
__global__ void __launch_bounds__(256, 8) knn_sel3_kernel(const float* __restrict__ G,
                                                          const float* __restrict__ sq,
                                                          int* __restrict__ idx, int b0) {
    __shared__ float ssq[PP];
    const int bg = blockIdx.y, b = b0 + bg, tid = threadIdx.x;
    const int lane = tid & 63, wv = tid >> 6;
    const float* sqc = sq + (size_t)b * PP;
    for (int i = tid; i < PP; i += 256) ssq[i] = sqc[i];
    __syncthreads();
    const int ql = blockIdx.x * 4 + wv;
    const float4* Gr = (const float4*)(G + ((size_t)bg * PP + ql) * PP);
    const float4* sq4 = (const float4*)ssq;
    const float sqQ = ssq[ql];
    REP32(DECLD)
    SEL_CHUNK(0, 0, 1, 2, 3)   SEL_CHUNK(1, 4, 5, 6, 7)
    SEL_CHUNK(2, 8, 9, 10, 11) SEL_CHUNK(3, 12, 13, 14, 15)
    SEL_CHUNK(4, 16, 17, 18, 19) SEL_CHUNK(5, 20, 21, 22, 23)
    SEL_CHUNK(6, 24, 25, 26, 27) SEL_CHUNK(7, 28, 29, 30, 31)
    int* orow = idx + ((size_t)b * PP + ql) * KK;
    TOPK16_BODY(orow, b * PP)
}

// ============ fused BN-apply(+ReLU, in place) + row sum-of-squares ============
__global__ void bnsq_kernel(float* __restrict__ h, const float* __restrict__ a,
                            const float* __restrict__ bs, float* __restrict__ sq, int C) {
    const int lane = threadIdx.x & 63;
    const int row = blockIdx.x * 4 + (threadIdx.x >> 6);
    float* hr = h + (size_t)row * C;
    float s = 0.f;
    for (int d = lane; d < C; d += 64) {
        float v = fmaf(hr[d], a[d], bs[d]);
        v = v > 0.f ? v : 0.f;
        hr[d] = v;
        s += v * v;
    }
    #pragma unroll
    for (int off = 32; off; off >>= 1) s += __shfl_down(s, off);
    if (lane == 0) sq[row] = s;
}

// ============ BN final reduce: one block per column over R partials ============
__global__ void bn_final2_kernel(const float* __restrict__ ps, const float* __restrict__ pss,
                                 const float* __restrict__ g, const float* __restrict__ be,
                                 float* __restrict__ a, float* __restrict__ bs,
                                 int C, int R) {
    const int c = blockIdx.x, tid = threadIdx.x;
    const int lane = tid & 63, wv = tid >> 6;
    __shared__ float sh_s[4], sh_ss[4];
    float s = 0.f, ss = 0.f;
    for (int r = tid; r < R; r += 256) {
        s  += ps [(size_t)r * C + c];
        ss += pss[(size_t)r * C + c];
    }
    #pragma unroll
    for (int off = 32; off; off >>= 1) {
        s  += __shfl_down(s, off);
        ss += __shfl_down(ss, off);
    }
    if (lane == 0) { sh_s[wv] = s; sh_ss[wv] = ss; }
    __syncthreads();
    if (tid == 0) {
        float ts = sh_s[0] + sh_s[1] + sh_s[2] + sh_s[3];
        float tss = sh_ss[0] + sh_ss[1] + sh_ss[2] + sh_ss[3];
        float m = ts / (float)NN;
        float v = tss / (float)NN - m * m;
        float rstd = rsqrtf(v + EPSF);
        float aa = rstd * g[c];
        a[c] = aa;
        bs[c] = be[c] - m * aa;
    }
}

// ============================ segment max pool with fused BN+ReLU ============================
__global__ void segmax_bn_kernel(const float* __restrict__ h, const float* __restrict__ a,
                                 const float* __restrict__ bs, float* __restrict__ pooled) {
    const int b = blockIdx.x, chunk = blockIdx.y, tid = threadIdx.x;
    const int r0 = chunk * 128;
    for (int cb = 0; cb < 512; cb += 256) {
        int c = cb + tid;
        float aa = a[c], bb2 = bs[c];
        float m = 0.f;   // relu'd values >= 0
        for (int r = r0; r < r0 + 128; ++r) {
            float v = fmaf(h[((size_t)b * PP + r) * 512 + c], aa, bb2);
            v = v > 0.f ? v : 0.f;
            m = fmaxf(m, v);
        }
        atomicMax((int*)&pooled[b * 512 + c], __float_as_int(m));
    }
}

// ============ bottleneck GEMM (M=16, K=512, Nc=512): K-split two-stage ============
__global__ void gemm16_part_kernel(const float* __restrict__ A, const float* __restrict__ W,
                                   float* __restrict__ part) {
    __shared__ float As[16][68];
    const int tid = threadIdx.x;
    const int n0 = blockIdx.x * 64, k0 = blockIdx.y * 64;
    for (int i = tid; i < 16 * 64; i += 256) {
        int row = i >> 6, kk = i & 63;
        As[row][kk] = A[(size_t)row * 512 + k0 + kk];
    }
    __syncthreads();
    const int col = n0 + (tid & 63);
    const int rg = (tid >> 6) * 4;
    float a0 = 0.f, a1 = 0.f, a2 = 0.f, a3 = 0.f;
    #pragma unroll 8
    for (int kk = 0; kk < 64; ++kk) {
        float w = W[(size_t)(k0 + kk) * 512 + col];
        a0 = fmaf(As[rg + 0][kk], w, a0);
        a1 = fmaf(As[rg + 1][kk], w, a1);
        a2 = fmaf(As[rg + 2][kk], w, a2);
        a3 = fmaf(As[rg + 3][kk], w, a3);
    }
    float* p = part + (size_t)blockIdx.y * 16 * 512;
    p[(size_t)(rg + 0) * 512 + col] = a0;
    p[(size_t)(rg + 1) * 512 + col] = a1;
    p[(size_t)(rg + 2) * 512 + col] = a2;
    p[(size_t)(rg + 3) * 512 + col] = a3;
}

__global__ void gemm16_reduce_kernel(const float* __restrict__ part,
                                     const float* __restrict__ bias,
                                     float* __restrict__ C) {
    int i = blockIdx.x * 256 + threadIdx.x;    // 8192 outputs
    int col = i & 511, row = i >> 9;
    float s = bias[col];
    #pragma unroll
    for (int ks = 0; ks < 8; ++ks)
        s += part[((size_t)ks * 16 + row) * 512 + col];
    C[i] = s;
}

// ============================ BN over 16 rows + ReLU (in place) ============================
__global__ void bn16_kernel(float* __restrict__ h, const float* __restrict__ g,
                            const float* __restrict__ be) {
    int c = blockIdx.x * 256 + threadIdx.x;
    if (c >= 512) return;
    float s = 0.f, ss = 0.f;
    for (int r = 0; r < 16; ++r) { float v = h[r * 512 + c]; s += v; ss += v * v; }
    float m = s / 16.f;
    float var = ss / 16.f - m * m;
    float rstd = rsqrtf(var + EPSF);
    float aa = rstd * g[c], bb = be[c] - m * aa;
    for (int r = 0; r < 16; ++r) {
        float v = h[r * 512 + c] * aa + bb;
        h[r * 512 + c] = v > 0.f ? v : 0.f;
    }
}

// ============================ host ============================
static inline void* wsAlloc(char*& w, size_t bytes) {
    void* p = (void*)w;
    w += (bytes + 255) & ~(size_t)255;
    return p;
}

extern "C" void kernel_launch(void* const* d_in, const int* in_sizes, int n_in,
                              void* d_out, int out_size, void* d_ws, size_t ws_size,
                              hipStream_t stream) {
    (void)in_sizes; (void)n_in; (void)out_size; (void)ws_size;
    const float* x    = (const float*)d_in[0];
    const float* W1   = (const float*)d_in[2];
    const float* b1   = (const float*)d_in[3];
    const float* g1   = (const float*)d_in[4];
    const float* be1  = (const float*)d_in[5];
    const float* W2   = (const float*)d_in[6];
    const float* b2   = (const float*)d_in[7];
    const float* g2   = (const float*)d_in[8];
    const float* be2  = (const float*)d_in[9];
    const float* W3   = (const float*)d_in[10];
    const float* b3   = (const float*)d_in[11];
    const float* g3   = (const float*)d_in[12];
    const float* be3  = (const float*)d_in[13];
    const float* Wg1  = (const float*)d_in[14];
    const float* bg1  = (const float*)d_in[15];
    const float* gg1  = (const float*)d_in[16];
    const float* beg1 = (const float*)d_in[17];
    const float* Wg2  = (const float*)d_in[18];
    const float* bg2  = (const float*)d_in[19];
    const float* gg2  = (const float*)d_in[20];
    const float* beg2 = (const float*)d_in[21];
    const float* Wn1  = (const float*)d_in[22];
    const float* bn1  = (const float*)d_in[23];
    const float* gn1  = (const float*)d_in[24];
    const float* ben1 = (const float*)d_in[25];
    const float* Wn2  = (const float*)d_in[26];
    const float* bn2  = (const float*)d_in[27];

    char* w = (char*)d_ws;
    float* sq     = (float*)wsAlloc(w, (size_t)NN * 4);
    int*   idx    = (int*)  wsAlloc(w, (size_t)NN * KK * 4);
    float* h0     = (float*)wsAlloc(w, (size_t)NN * 12 * 4);
    float* hA     = (float*)wsAlloc(w, (size_t)NN * 64 * 4);
    float* hB     = (float*)wsAlloc(w, (size_t)NN * 64 * 4);
    float* hg1    = (float*)wsAlloc(w, (size_t)NN * 128 * 4);
    float* ag2    = (float*)wsAlloc(w, (size_t)NN * 128 * 4);
    float* hg2    = (float*)wsAlloc(w, (size_t)NN * 512 * 4);   // 64 MiB; doubles as G during KNN
    float* ps     = (float*)wsAlloc(w, (size_t)(NN / 64) * 512 * 4);
    float* pss    = (float*)wsAlloc(w, (size_t)(NN / 64) * 512 * 4);
    float* bnA    = (float*)wsAlloc(w, 512 * 4);
    float* bnS    = (float*)wsAlloc(w, 512 * 4);
    float* pooled = (float*)wsAlloc(w, 16 * 512 * 4);
    float* t16    = (float*)wsAlloc(w, 16 * 512 * 4);
    (void)hB; (void)ag2;

    // ---- local covariance features ----
    knn3v3_kernel<<<dim3(PP / 8, BB), 512, 0, stream>>>(x, idx);
    cov_kernel<<<NN / 256, 256, 0, stream>>>(x, idx, h0);

    // 64-tile dense (C=64 layers): R = NN/64 partial rows.
    auto dense = [&](const float* in, int K, int C, const float* Wp, const float* bp,
                     const float* gp, const float* bep,
                     const float* aInP, const float* bInP, float* out) {
        gemm_stats_kernel<<<dim3(C / 64, NN / 64), 256, 0, stream>>>(
            in, Wp, bp, out, aInP, bInP, ps, pss, K, C);
        bn_final2_kernel<<<C, 256, 0, stream>>>(ps, pss, gp, bep, bnA, bnS, C, NN / 64);
    };
    // 128-tile dense with fused gather-max A (graph layers): R = NN/128.
    auto dense128g = [&](const float* fIn, int K, int C, const float* Wp, const float* bp,
                         const float* gp, const float* bep, float* out) {
        gemm_gather_stats128_kernel<<<dim3(C / 128, NN / 128), 256, 0, stream>>>(
            fIn, idx, Wp, bp, out, ps, pss, K, C);
        bn_final2_kernel<<<C, 256, 0, stream>>>(ps, pss, gp, bep, bnA, bnS, C, NN / 128);
    };

    // point MLP: BN of layer n applied on the A-load of layer n+1 (single consumer)
    dense(h0, 12, 64, W1, b1, g1, be1, nullptr, nullptr, hA);   // hA = raw1; stats1
    dense(hA, 64, 64, W2, b2, g2, be2, bnA, bnS, hB);           // hB = raw2; stats2
    dense(hB, 64, 64, W3, b3, g3, be3, bnA, bnS, hA);           // hA = raw3; stats3
    bnsq_kernel<<<NN / 4, 256, 0, stream>>>(hA, bnA, bnS, sq, 64);   // BN+ReLU in place + sumsq

    // KNN in feature space: symmetric gram into hg2 (dead until the final dense).
    float* Gbuf = hg2;
    auto knn_feat = [&](const float* f, int D) {
        for (int b0 = 0; b0 < BB; b0 += 4) {
            gram128_sym_kernel<<<dim3(136, 4), 256, 0, stream>>>(f, Gbuf, D, b0);
            knn_sel3_kernel<<<dim3(PP / 4, 4), 256, 0, stream>>>(Gbuf, sq, idx, b0);
        }
    };

    // ---- graph layer 1 (64-d knn): gather-max fused into GEMM A-stage ----
    knn_feat(hA, 64);
    dense128g(hA, 64, 128, Wg1, bg1, gg1, beg1, hg1);
    bnsq_kernel<<<NN / 4, 256, 0, stream>>>(hg1, bnA, bnS, sq, 128);  // BN+ReLU + sumsq

    // ---- graph layer 2 (128-d knn): gather-max fused into GEMM A-stage ----
    knn_feat(hg1, 128);
    dense128g(hg1, 128, 512, Wg2, bg2, gg2, beg2, hg2);         // hg2 now real output

    // ---- global max pool (BN+ReLU fused) + bottleneck (two-stage K-split GEMMs) ----
    hipMemsetAsync(pooled, 0, 16 * 512 * 4, stream);
    segmax_bn_kernel<<<dim3(BB, 16), 256, 0, stream>>>(hg2, bnA, bnS, pooled);
    gemm16_part_kernel<<<dim3(8, 8), 256, 0, stream>>>(pooled, Wn1, ps);
    gemm16_reduce_kernel<<<32, 256, 0, stream>>>(ps, bn1, t16);
    bn16_kernel<<<2, 256, 0, stream>>>(t16, gn1, ben1);
    gemm16_part_kernel<<<dim3(8, 8), 256, 0, stream>>>(t16, Wn2, ps);
    gemm16_reduce_kernel<<<32, 256, 0, stream>>>(ps, bn2, (float*)d_out);
}

// Round 16
// 825.707 us; speedup vs baseline: 1.8273x; 1.8273x over previous
//
#include <hip/hip_runtime.h>

#define BB 16
#define PP 2048
#define NN 32768   // BB*PP
#define KK 16
#define EPSF 1e-5f

// ============================================================
// Wave-parallel top-16 selection (R12 known-good — FROZEN).
// R13's deeper Q-caching spilled (360 MB scratch, 130us) -> this exact form
// (88us, ~4MB, VALUBusy 93%). Do not add live state to this loop without
// checking FETCH/WRITE_SIZE afterwards.
// R15 ledger: gather loads must NOT be fused into register-heavy GEMM bodies
// (acc spills at 64-VGPR cap; per-XCD L2 is only 4 MiB so >4MiB scatter
// working sets thrash to HBM). gathermax4 standalone is the known-good form.
// ============================================================
#define REP32(M) M(0) M(1) M(2) M(3) M(4) M(5) M(6) M(7) M(8) M(9) M(10) M(11) \
                 M(12) M(13) M(14) M(15) M(16) M(17) M(18) M(19) M(20) M(21) M(22) \
                 M(23) M(24) M(25) M(26) M(27) M(28) M(29) M(30) M(31)
#define DECLD(j) float D##j;

#define MPS(EO, FO, DA, JA, DB, JB) \
    { bool lt_ = (DB) < (DA); EO = lt_ ? (DB) : (DA); FO = lt_ ? (JB) : (JA); }

#define GTREE(GV, GS, dA,sA, dB,sB, dC,sC, dD,sD, dE,sE, dF,sF, dG,sG, dH,sH) { \
    float p0_, p1_, p2_, p3_, q0_, q1_; int o0_, o1_, o2_, o3_, r0_, r1_; \
    MPS(p0_, o0_, dA, sA, dB, sB) \
    MPS(p1_, o1_, dC, sC, dD, sD) \
    MPS(p2_, o2_, dE, sE, dF, sF) \
    MPS(p3_, o3_, dG, sG, dH, sH) \
    MPS(q0_, r0_, p0_, o0_, p1_, o1_) \
    MPS(q1_, r1_, p2_, o2_, p3_, o3_) \
    MPS(GV, GS, q0_, r0_, q1_, r1_) }

#define GT0 GTREE(G0v,H0v, D0,0,D1,1,D2,2,D3,3,D4,4,D5,5,D6,6,D7,7)
#define GT1 GTREE(G1v,H1v, D8,8,D9,9,D10,10,D11,11,D12,12,D13,13,D14,14,D15,15)
#define GT2 GTREE(G2v,H2v, D16,16,D17,17,D18,18,D19,19,D20,20,D21,21,D22,22,D23,23)
#define GT3 GTREE(G3v,H3v, D24,24,D25,25,D26,26,D27,27,D28,28,D29,29,D30,30,D31,31)

#define INVG0 \
    D0 = (wslot_ == 0) ? 3.4e38f : D0;  D1 = (wslot_ == 1) ? 3.4e38f : D1; \
    D2 = (wslot_ == 2) ? 3.4e38f : D2;  D3 = (wslot_ == 3) ? 3.4e38f : D3; \
    D4 = (wslot_ == 4) ? 3.4e38f : D4;  D5 = (wslot_ == 5) ? 3.4e38f : D5; \
    D6 = (wslot_ == 6) ? 3.4e38f : D6;  D7 = (wslot_ == 7) ? 3.4e38f : D7;
#define INVG1 \
    D8  = (wslot_ == 8)  ? 3.4e38f : D8;  D9  = (wslot_ == 9)  ? 3.4e38f : D9; \
    D10 = (wslot_ == 10) ? 3.4e38f : D10; D11 = (wslot_ == 11) ? 3.4e38f : D11; \
    D12 = (wslot_ == 12) ? 3.4e38f : D12; D13 = (wslot_ == 13) ? 3.4e38f : D13; \
    D14 = (wslot_ == 14) ? 3.4e38f : D14; D15 = (wslot_ == 15) ? 3.4e38f : D15;
#define INVG2 \
    D16 = (wslot_ == 16) ? 3.4e38f : D16; D17 = (wslot_ == 17) ? 3.4e38f : D17; \
    D18 = (wslot_ == 18) ? 3.4e38f : D18; D19 = (wslot_ == 19) ? 3.4e38f : D19; \
    D20 = (wslot_ == 20) ? 3.4e38f : D20; D21 = (wslot_ == 21) ? 3.4e38f : D21; \
    D22 = (wslot_ == 22) ? 3.4e38f : D22; D23 = (wslot_ == 23) ? 3.4e38f : D23;
#define INVG3 \
    D24 = (wslot_ == 24) ? 3.4e38f : D24; D25 = (wslot_ == 25) ? 3.4e38f : D25; \
    D26 = (wslot_ == 26) ? 3.4e38f : D26; D27 = (wslot_ == 27) ? 3.4e38f : D27; \
    D28 = (wslot_ == 28) ? 3.4e38f : D28; D29 = (wslot_ == 29) ? 3.4e38f : D29; \
    D30 = (wslot_ == 30) ? 3.4e38f : D30; D31 = (wslot_ == 31) ? 3.4e38f : D31;

#define TOPK16_BODY(OROW, BASE) { \
    float G0v, G1v, G2v, G3v; int H0v, H1v, H2v, H3v; \
    GT0 GT1 GT2 GT3 \
    int mykeep_ = 0; \
    for (int it_ = 0; it_ < KK; ++it_) { \
        float z_; int y_; \
        { float u0_, u1_; int v0_, v1_; \
          MPS(u0_, v0_, G0v, H0v, G1v, H1v) \
          MPS(u1_, v1_, G2v, H2v, G3v, H3v) \
          MPS(z_, y_, u0_, v0_, u1_, v1_) } \
        float v_ = z_; \
        _Pragma("unroll") \
        for (int off_ = 32; off_; off_ >>= 1) \
            v_ = fminf(v_, __shfl_xor(v_, off_)); \
        const int cil_ = ((y_ >> 2) << 8) + (y_ & 3) + (lane << 2); \
        unsigned long long mk_ = __ballot(z_ == v_); \
        int ci_; \
        if (__popcll(mk_) == 1) { \
            ci_ = __shfl(cil_, (int)(__ffsll((long long)mk_) - 1)); \
        } else { \
            ci_ = 0x7fffffff; \
            unsigned long long m2_ = mk_; \
            while (m2_) { \
                int l2_ = (int)(__ffsll((long long)m2_) - 1); \
                int c2_ = __shfl(cil_, l2_); \
                ci_ = c2_ < ci_ ? c2_ : ci_; \
                m2_ &= m2_ - 1; \
            } \
        } \
        const int wslot_ = ((ci_ >> 8) << 2) | (ci_ & 3); \
        if (lane == ((ci_ & 255) >> 2)) { \
            if (wslot_ < 8)       { INVG0 GT0 } \
            else if (wslot_ < 16) { INVG1 GT1 } \
            else if (wslot_ < 24) { INVG2 GT2 } \
            else                  { INVG3 GT3 } \
        } \
        mykeep_ = (lane == it_) ? ci_ : mykeep_; \
    } \
    if (lane < KK) (OROW)[lane] = (BASE) + mykeep_; \
}

// ============================ 3-D KNN (ONE query per wave, 8 waves/block) ============================
#define KNN3_CHUNK(jj, a0, a1, a2, a3) { \
    float4 cx = px4[jj * 64 + lane]; \
    float4 cy = py4[jj * 64 + lane]; \
    float4 cz = pz4[jj * 64 + lane]; \
    float4 cs = pq4[jj * 64 + lane]; \
    const int c0_ = jj * 256 + lane * 4; \
    D##a0 = sqQ + cs.x - 2.f * (qx * cx.x + qy * cy.x + qz * cz.x); if (c0_ + 0 == q) D##a0 += 1e10f; \
    D##a1 = sqQ + cs.y - 2.f * (qx * cx.y + qy * cy.y + qz * cz.y); if (c0_ + 1 == q) D##a1 += 1e10f; \
    D##a2 = sqQ + cs.z - 2.f * (qx * cx.z + qy * cy.z + qz * cz.z); if (c0_ + 2 == q) D##a2 += 1e10f; \
    D##a3 = sqQ + cs.w - 2.f * (qx * cx.w + qy * cy.w + qz * cz.w); if (c0_ + 3 == q) D##a3 += 1e10f; \
}

__global__ void __launch_bounds__(512, 8) knn3v3_kernel(const float* __restrict__ x,
                                                        int* __restrict__ idx) {
    __shared__ float spx[PP], spy[PP], spz[PP], ssq[PP];
    const int b = blockIdx.y, tid = threadIdx.x;
    const float* xc = x + (size_t)b * PP * 3;
    for (int i = tid; i < PP; i += 512) {
        float a = xc[i * 3 + 0], b2 = xc[i * 3 + 1], c2 = xc[i * 3 + 2];
        spx[i] = a; spy[i] = b2; spz[i] = c2;
        ssq[i] = a * a + b2 * b2 + c2 * c2;
    }
    __syncthreads();
    const int lane = tid & 63, wv = tid >> 6;
    const float4* px4 = (const float4*)spx;
    const float4* py4 = (const float4*)spy;
    const float4* pz4 = (const float4*)spz;
    const float4* pq4 = (const float4*)ssq;
    const int q = blockIdx.x * 8 + wv;
    const float qx = spx[q], qy = spy[q], qz = spz[q], sqQ = ssq[q];
    REP32(DECLD)
    KNN3_CHUNK(0, 0, 1, 2, 3)   KNN3_CHUNK(1, 4, 5, 6, 7)
    KNN3_CHUNK(2, 8, 9, 10, 11) KNN3_CHUNK(3, 12, 13, 14, 15)
    KNN3_CHUNK(4, 16, 17, 18, 19) KNN3_CHUNK(5, 20, 21, 22, 23)
    KNN3_CHUNK(6, 24, 25, 26, 27) KNN3_CHUNK(7, 28, 29, 30, 31)
    int* orow = idx + ((size_t)b * PP + q) * KK;
    TOPK16_BODY(orow, b * PP)
}

// ============================ local covariance -> h0[N,12] ============================
__global__ void cov_kernel(const float* __restrict__ x, const int* __restrict__ idx,
                           float* __restrict__ h0) {
    int p = blockIdx.x * 256 + threadIdx.x;
    if (p >= NN) return;
    const int* ip = idx + (size_t)p * KK;
    float nx[KK], ny[KK], nz[KK];
    float mx = 0.f, my = 0.f, mz = 0.f;
    #pragma unroll
    for (int k = 0; k < KK; ++k) {
        int j = ip[k];
        float a = x[j * 3 + 0], b2 = x[j * 3 + 1], c2 = x[j * 3 + 2];
        nx[k] = a; ny[k] = b2; nz[k] = c2;
        mx += a; my += b2; mz += c2;
    }
    mx *= (1.f / KK); my *= (1.f / KK); mz *= (1.f / KK);
    float cxx = 0, cxy = 0, cxz = 0, cyy = 0, cyz = 0, czz = 0;
    #pragma unroll
    for (int k = 0; k < KK; ++k) {
        float a = nx[k] - mx, b2 = ny[k] - my, c2 = nz[k] - mz;
        cxx += a * a;  cxy += a * b2;  cxz += a * c2;
        cyy += b2 * b2; cyz += b2 * c2; czz += c2 * c2;
    }
    const float s = 1.f / KK;
    float* o = h0 + (size_t)p * 12;
    o[0] = x[p * 3 + 0]; o[1] = x[p * 3 + 1]; o[2] = x[p * 3 + 2];
    o[3] = cxx * s; o[4]  = cxy * s; o[5]  = cxz * s;
    o[6] = cxy * s; o[7]  = cyy * s; o[8]  = cyz * s;
    o[9] = cxz * s; o[10] = cyz * s; o[11] = czz * s;
}

// ============ GEMM (64-tile) + fused BN-stats epilogue (+ optional BN-ReLU on A-load) ============
__global__ void gemm_stats_kernel(const float* __restrict__ A, const float* __restrict__ W,
                                  const float* __restrict__ bias, float* __restrict__ C,
                                  const float* __restrict__ aIn, const float* __restrict__ bIn,
                                  float* __restrict__ ps, float* __restrict__ pss,
                                  int K, int Nc) {
    __shared__ float As[16][68];
    __shared__ float Ws[16][68];
    const int tid = threadIdx.x;
    const int m0 = blockIdx.y * 64, n0 = blockIdx.x * 64;
    const int tx = tid & 15, ty = tid >> 4;
    float acc[4][4] = {};
    for (int k0 = 0; k0 < K; k0 += 16) {
        {
            int kk = tid & 15, mp0 = tid >> 4;
            bool kok = (k0 + kk < K);
            float ai = 1.f, bi = 0.f;
            if (aIn && kok) { ai = aIn[k0 + kk]; bi = bIn[k0 + kk]; }
            #pragma unroll
            for (int i = 0; i < 4; ++i) {
                int mp = mp0 + i * 16;
                float v = 0.f;
                if (kok) {
                    v = A[(size_t)(m0 + mp) * K + k0 + kk];
                    if (aIn) { v = fmaf(v, ai, bi); v = v > 0.f ? v : 0.f; }
                }
                As[kk][mp] = v;
            }
            int nn = tid & 63, kb = tid >> 6;
            #pragma unroll
            for (int i = 0; i < 4; ++i) {
                int kk3 = kb + i * 4;
                float v = 0.f;
                if (k0 + kk3 < K) v = W[(size_t)(k0 + kk3) * Nc + n0 + nn];
                Ws[kk3][nn] = v;
            }
        }
        __syncthreads();
        #pragma unroll
        for (int kk = 0; kk < 16; ++kk) {
            float4 a4 = *(const float4*)&As[kk][ty * 4];
            float4 b4 = *(const float4*)&Ws[kk][tx * 4];
            float av[4] = {a4.x, a4.y, a4.z, a4.w};
            float bv[4] = {b4.x, b4.y, b4.z, b4.w};
            #pragma unroll
            for (int i = 0; i < 4; ++i)
                #pragma unroll
                for (int j = 0; j < 4; ++j)
                    acc[i][j] = fmaf(av[i], bv[j], acc[i][j]);
        }
        __syncthreads();
    }
    float4 bb = *(const float4*)&bias[n0 + tx * 4];
    float bvv[4] = {bb.x, bb.y, bb.z, bb.w};
    float colS[4] = {}, colSS[4] = {};
    #pragma unroll
    for (int i = 0; i < 4; ++i) {
        int m = m0 + ty * 4 + i;
        float r[4];
        #pragma unroll
        for (int j = 0; j < 4; ++j) {
            r[j] = acc[i][j] + bvv[j];
            colS[j] += r[j];
            colSS[j] += r[j] * r[j];
        }
        float4 rr = {r[0], r[1], r[2], r[3]};
        *(float4*)&C[(size_t)m * Nc + n0 + tx * 4] = rr;
    }
    #pragma unroll
    for (int j = 0; j < 4; ++j) { As[ty][tx * 4 + j] = colS[j]; Ws[ty][tx * 4 + j] = colSS[j]; }
    __syncthreads();
    if (tid < 64) {
        float s = 0.f, ss = 0.f;
        #pragma unroll
        for (int t = 0; t < 16; ++t) { s += As[t][tid]; ss += Ws[t][tid]; }
        ps [(size_t)blockIdx.y * Nc + n0 + tid] = s;
        pss[(size_t)blockIdx.y * Nc + n0 + tid] = ss;
    }
}

// ============ GEMM (128-tile, 8x8 acc) + fused BN-stats epilogue ============
__global__ void gemm_stats128_kernel(const float* __restrict__ A, const float* __restrict__ W,
                                     const float* __restrict__ bias, float* __restrict__ C,
                                     float* __restrict__ ps, float* __restrict__ pss,
                                     int K, int Nc) {
    __shared__ float As[16][136];
    __shared__ float Ws[16][136];
    const int tid = threadIdx.x;
    const int m0 = blockIdx.y * 128, n0 = blockIdx.x * 128;
    const int tx = tid & 15, ty = tid >> 4;
    float acc[8][8] = {};
    for (int k0 = 0; k0 < K; k0 += 16) {
        {
            const int kk = tid & 15, r0 = tid >> 4;
            #pragma unroll
            for (int i = 0; i < 8; ++i) {
                int r = r0 + i * 16;
                As[kk][r] = A[(size_t)(m0 + r) * K + k0 + kk];
            }
            const int col = tid & 127, kb = tid >> 7;
            #pragma unroll
            for (int i = 0; i < 8; ++i) {
                int kk3 = kb + i * 2;
                Ws[kk3][col] = W[(size_t)(k0 + kk3) * Nc + n0 + col];
            }
        }
        __syncthreads();
        #pragma unroll
        for (int kk2 = 0; kk2 < 16; ++kk2) {
            float4 a0 = *(const float4*)&As[kk2][ty * 8];
            float4 a1 = *(const float4*)&As[kk2][ty * 8 + 4];
            float4 b0 = *(const float4*)&Ws[kk2][tx * 8];
            float4 b1 = *(const float4*)&Ws[kk2][tx * 8 + 4];
            float av[8] = {a0.x, a0.y, a0.z, a0.w, a1.x, a1.y, a1.z, a1.w};
            float bv[8] = {b0.x, b0.y, b0.z, b0.w, b1.x, b1.y, b1.z, b1.w};
            #pragma unroll
            for (int i = 0; i < 8; ++i)
                #pragma unroll
                for (int j = 0; j < 8; ++j)
                    acc[i][j] = fmaf(av[i], bv[j], acc[i][j]);
        }
        __syncthreads();
    }
    float4 bb0 = *(const float4*)&bias[n0 + tx * 8];
    float4 bb1 = *(const float4*)&bias[n0 + tx * 8 + 4];
    float bvv[8] = {bb0.x, bb0.y, bb0.z, bb0.w, bb1.x, bb1.y, bb1.z, bb1.w};
    float colS[8] = {}, colSS[8] = {};
    #pragma unroll
    for (int i = 0; i < 8; ++i) {
        int m = m0 + ty * 8 + i;
        float r[8];
        #pragma unroll
        for (int j = 0; j < 8; ++j) {
            r[j] = acc[i][j] + bvv[j];
            colS[j] += r[j];
            colSS[j] += r[j] * r[j];
        }
        float4 r0v = {r[0], r[1], r[2], r[3]};
        float4 r1v = {r[4], r[5], r[6], r[7]};
        float* row = &C[(size_t)m * Nc + n0 + tx * 8];
        *(float4*)row = r0v;
        *(float4*)(row + 4) = r1v;
    }
    #pragma unroll
    for (int j = 0; j < 8; ++j) { As[ty][tx * 8 + j] = colS[j]; Ws[ty][tx * 8 + j] = colSS[j]; }
    __syncthreads();
    if (tid < 128) {
        float s = 0.f, ss = 0.f;
        #pragma unroll
        for (int t = 0; t < 16; ++t) { s += As[t][tid]; ss += Ws[t][tid]; }
        ps [(size_t)blockIdx.y * Nc + n0 + tid] = s;
        pss[(size_t)blockIdx.y * Nc + n0 + tid] = ss;
    }
}

// ============ SYMMETRIC gram, 128x128 tiles, upper triangle + mirrored write ============
__global__ void gram128_sym_kernel(const float* __restrict__ f, float* __restrict__ G,
                                   int D, int b0) {
    __shared__ float As[16][132];
    __shared__ float Bs[16][132];
    int t = blockIdx.x, ti = 0;
    while (t >= 16 - ti) { t -= 16 - ti; ++ti; }
    const int tj = ti + t;                    // ti <= tj
    const int pm0 = ti * 128, qn0 = tj * 128;
    const float* fc = f + (size_t)(b0 + blockIdx.y) * PP * D;
    float* Gb = G + (size_t)blockIdx.y * PP * PP;
    const int tid = threadIdx.x;
    const int tx = tid & 15, ty = tid >> 4;
    float acc[8][8] = {};
    for (int k0 = 0; k0 < D; k0 += 16) {
        const int kk = tid & 15, r0 = tid >> 4;
        #pragma unroll
        for (int i = 0; i < 8; ++i) {
            int r = r0 + i * 16;
            As[kk][r] = fc[(size_t)(pm0 + r) * D + k0 + kk];
            Bs[kk][r] = fc[(size_t)(qn0 + r) * D + k0 + kk];
        }
        __syncthreads();
        #pragma unroll
        for (int kk2 = 0; kk2 < 16; ++kk2) {
            float4 a0 = *(const float4*)&As[kk2][ty * 8];
            float4 a1 = *(const float4*)&As[kk2][ty * 8 + 4];
            float4 b0v = *(const float4*)&Bs[kk2][tx * 8];
            float4 b1v = *(const float4*)&Bs[kk2][tx * 8 + 4];
            float av[8] = {a0.x, a0.y, a0.z, a0.w, a1.x, a1.y, a1.z, a1.w};
            float bv[8] = {b0v.x, b0v.y, b0v.z, b0v.w, b1v.x, b1v.y, b1v.z, b1v.w};
            #pragma unroll
            for (int i = 0; i < 8; ++i)
                #pragma unroll
                for (int j = 0; j < 8; ++j)
                    acc[i][j] = fmaf(av[i], bv[j], acc[i][j]);
        }
        __syncthreads();
    }
    #pragma unroll
    for (int i = 0; i < 8; ++i) {
        float4 r0v = {acc[i][0], acc[i][1], acc[i][2], acc[i][3]};
        float4 r1v = {acc[i][4], acc[i][5], acc[i][6], acc[i][7]};
        float* row = Gb + (size_t)(pm0 + ty * 8 + i) * PP + qn0 + tx * 8;
        *(float4*)row = r0v;
        *(float4*)(row + 4) = r1v;
    }
    if (ti != tj) {
        #pragma unroll
        for (int j = 0; j < 8; ++j) {
            float4 c0 = {acc[0][j], acc[1][j], acc[2][j], acc[3][j]};
            float4 c1 = {acc[4][j], acc[5][j], acc[6][j], acc[7][j]};
            float* row = Gb + (size_t)(qn0 + tx * 8 + j) * PP + pm0 + ty * 8;
            *(float4*)row = c0;
            *(float4*)(row + 4) = c1;
        }
    }
}

// ============ top-16 from full gram rows (wave per query, batch-group G) ============
#define SEL_CHUNK(jj, a0, a1, a2, a3) { \
    float4 g4 = Gr[jj * 64 + lane]; \
    float4 s4 = sq4[jj * 64 + lane]; \
    const int c0_ = jj * 256 + lane * 4; \
    D##a0 = sqQ + s4.x - 2.f * g4.x; if (c0_ + 0 == ql) D##a0 += 1e10f; \
    D##a1 = sqQ + s4.y - 2.f * g4.y; if (c0_ + 1 == ql) D##a1 += 1e10f; \
    D##a2 = sqQ + s4.z - 2.f * g4.z; if (c0_ + 2 == ql) D##a2 += 1e10f; \
    D##a3 = sqQ + s4.w - 2.f * g4.w; if (c0_ + 3 == ql) D##a3 += 1e10f; \
}

// 8 blocks/CU -> 32 waves/CU (8 KB LDS each).
__global__ void __launch_bounds__(256, 8) knn_sel3_kernel(const float* __restrict__ G,
                                                          const float* __restrict__ sq,
                                                          int* __restrict__ idx, int b0) {
    __shared__ float ssq[PP];
    const int bg = blockIdx.y, b = b0 + bg, tid = threadIdx.x;
    const int lane = tid & 63, wv = tid >> 6;
    const float* sqc = sq + (size_t)b * PP;
    for (int i = tid; i < PP; i += 256) ssq[i] = sqc[i];
    __syncthreads();
    const int ql = blockIdx.x * 4 + wv;
    const float4* Gr = (const float4*)(G + ((size_t)bg * PP + ql) * PP);
    const float4* sq4 = (const float4*)ssq;
    const float sqQ = ssq[ql];
    REP32(DECLD)
    SEL_CHUNK(0, 0, 1, 2, 3)   SEL_CHUNK(1, 4, 5, 6, 7)
    SEL_CHUNK(2, 8, 9, 10, 11) SEL_CHUNK(3, 12, 13, 14, 15)
    SEL_CHUNK(4, 16, 17, 18, 19) SEL_CHUNK(5, 20, 21, 22, 23)
    SEL_CHUNK(6, 24, 25, 26, 27) SEL_CHUNK(7, 28, 29, 30, 31)
    int* orow = idx + ((size_t)b * PP + ql) * KK;
    TOPK16_BODY(orow, b * PP)
}

// ============ fused BN-apply(+ReLU, in place) + row sum-of-squares ============
__global__ void bnsq_kernel(float* __restrict__ h, const float* __restrict__ a,
                            const float* __restrict__ bs, float* __restrict__ sq, int C) {
    const int lane = threadIdx.x & 63;
    const int row = blockIdx.x * 4 + (threadIdx.x >> 6);
    float* hr = h + (size_t)row * C;
    float s = 0.f;
    for (int d = lane; d < C; d += 64) {
        float v = fmaf(hr[d], a[d], bs[d]);
        v = v > 0.f ? v : 0.f;
        hr[d] = v;
        s += v * v;
    }
    #pragma unroll
    for (int off = 32; off; off >>= 1) s += __shfl_down(s, off);
    if (lane == 0) sq[row] = s;
}

// ============================ gather + max over K neighbors (float4 channels) ============================
__global__ void gathermax4_kernel(const float* __restrict__ f, const int* __restrict__ idx,
                                  float* __restrict__ agg, int C4) {
    size_t flat = (size_t)blockIdx.x * 256 + threadIdx.x;
    int c4 = (int)(flat % C4);
    int n = (int)(flat / C4);
    const int* ip = idx + (size_t)n * KK;
    const float4* f4 = (const float4*)f;
    float4 m = {-3.4e38f, -3.4e38f, -3.4e38f, -3.4e38f};
    #pragma unroll
    for (int k = 0; k < KK; ++k) {
        float4 v = f4[(size_t)ip[k] * C4 + c4];
        m.x = fmaxf(m.x, v.x); m.y = fmaxf(m.y, v.y);
        m.z = fmaxf(m.z, v.z); m.w = fmaxf(m.w, v.w);
    }
    ((float4*)agg)[flat] = m;
}

// ============ BN final reduce: one block per column over R partials ============
__global__ void bn_final2_kernel(const float* __restrict__ ps, const float* __restrict__ pss,
                                 const float* __restrict__ g, const float* __restrict__ be,
                                 float* __restrict__ a, float* __restrict__ bs,
                                 int C, int R) {
    const int c = blockIdx.x, tid = threadIdx.x;
    const int lane = tid & 63, wv = tid >> 6;
    __shared__ float sh_s[4], sh_ss[4];
    float s = 0.f, ss = 0.f;
    for (int r = tid; r < R; r += 256) {
        s  += ps [(size_t)r * C + c];
        ss += pss[(size_t)r * C + c];
    }
    #pragma unroll
    for (int off = 32; off; off >>= 1) {
        s  += __shfl_down(s, off);
        ss += __shfl_down(ss, off);
    }
    if (lane == 0) { sh_s[wv] = s; sh_ss[wv] = ss; }
    __syncthreads();
    if (tid == 0) {
        float ts = sh_s[0] + sh_s[1] + sh_s[2] + sh_s[3];
        float tss = sh_ss[0] + sh_ss[1] + sh_ss[2] + sh_ss[3];
        float m = ts / (float)NN;
        float v = tss / (float)NN - m * m;
        float rstd = rsqrtf(v + EPSF);
        float aa = rstd * g[c];
        a[c] = aa;
        bs[c] = be[c] - m * aa;
    }
}

// ============================ segment max pool with fused BN+ReLU ============================
__global__ void segmax_bn_kernel(const float* __restrict__ h, const float* __restrict__ a,
                                 const float* __restrict__ bs, float* __restrict__ pooled) {
    const int b = blockIdx.x, chunk = blockIdx.y, tid = threadIdx.x;
    const int r0 = chunk * 128;
    for (int cb = 0; cb < 512; cb += 256) {
        int c = cb + tid;
        float aa = a[c], bb2 = bs[c];
        float m = 0.f;   // relu'd values >= 0
        for (int r = r0; r < r0 + 128; ++r) {
            float v = fmaf(h[((size_t)b * PP + r) * 512 + c], aa, bb2);
            v = v > 0.f ? v : 0.f;
            m = fmaxf(m, v);
        }
        atomicMax((int*)&pooled[b * 512 + c], __float_as_int(m));
    }
}

// ============ bottleneck GEMM (M=16, K=512, Nc=512): K-split two-stage ============
__global__ void gemm16_part_kernel(const float* __restrict__ A, const float* __restrict__ W,
                                   float* __restrict__ part) {
    __shared__ float As[16][68];
    const int tid = threadIdx.x;
    const int n0 = blockIdx.x * 64, k0 = blockIdx.y * 64;
    for (int i = tid; i < 16 * 64; i += 256) {
        int row = i >> 6, kk = i & 63;
        As[row][kk] = A[(size_t)row * 512 + k0 + kk];
    }
    __syncthreads();
    const int col = n0 + (tid & 63);
    const int rg = (tid >> 6) * 4;
    float a0 = 0.f, a1 = 0.f, a2 = 0.f, a3 = 0.f;
    #pragma unroll 8
    for (int kk = 0; kk < 64; ++kk) {
        float w = W[(size_t)(k0 + kk) * 512 + col];
        a0 = fmaf(As[rg + 0][kk], w, a0);
        a1 = fmaf(As[rg + 1][kk], w, a1);
        a2 = fmaf(As[rg + 2][kk], w, a2);
        a3 = fmaf(As[rg + 3][kk], w, a3);
    }
    float* p = part + (size_t)blockIdx.y * 16 * 512;
    p[(size_t)(rg + 0) * 512 + col] = a0;
    p[(size_t)(rg + 1) * 512 + col] = a1;
    p[(size_t)(rg + 2) * 512 + col] = a2;
    p[(size_t)(rg + 3) * 512 + col] = a3;
}

__global__ void gemm16_reduce_kernel(const float* __restrict__ part,
                                     const float* __restrict__ bias,
                                     float* __restrict__ C) {
    int i = blockIdx.x * 256 + threadIdx.x;    // 8192 outputs
    int col = i & 511, row = i >> 9;
    float s = bias[col];
    #pragma unroll
    for (int ks = 0; ks < 8; ++ks)
        s += part[((size_t)ks * 16 + row) * 512 + col];
    C[i] = s;
}

// ============================ BN over 16 rows + ReLU (in place) ============================
__global__ void bn16_kernel(float* __restrict__ h, const float* __restrict__ g,
                            const float* __restrict__ be) {
    int c = blockIdx.x * 256 + threadIdx.x;
    if (c >= 512) return;
    float s = 0.f, ss = 0.f;
    for (int r = 0; r < 16; ++r) { float v = h[r * 512 + c]; s += v; ss += v * v; }
    float m = s / 16.f;
    float var = ss / 16.f - m * m;
    float rstd = rsqrtf(var + EPSF);
    float aa = rstd * g[c], bb = be[c] - m * aa;
    for (int r = 0; r < 16; ++r) {
        float v = h[r * 512 + c] * aa + bb;
        h[r * 512 + c] = v > 0.f ? v : 0.f;
    }
}

// ============================ host ============================
static inline void* wsAlloc(char*& w, size_t bytes) {
    void* p = (void*)w;
    w += (bytes + 255) & ~(size_t)255;
    return p;
}

extern "C" void kernel_launch(void* const* d_in, const int* in_sizes, int n_in,
                              void* d_out, int out_size, void* d_ws, size_t ws_size,
                              hipStream_t stream) {
    (void)in_sizes; (void)n_in; (void)out_size; (void)ws_size;
    const float* x    = (const float*)d_in[0];
    const float* W1   = (const float*)d_in[2];
    const float* b1   = (const float*)d_in[3];
    const float* g1   = (const float*)d_in[4];
    const float* be1  = (const float*)d_in[5];
    const float* W2   = (const float*)d_in[6];
    const float* b2   = (const float*)d_in[7];
    const float* g2   = (const float*)d_in[8];
    const float* be2  = (const float*)d_in[9];
    const float* W3   = (const float*)d_in[10];
    const float* b3   = (const float*)d_in[11];
    const float* g3   = (const float*)d_in[12];
    const float* be3  = (const float*)d_in[13];
    const float* Wg1  = (const float*)d_in[14];
    const float* bg1  = (const float*)d_in[15];
    const float* gg1  = (const float*)d_in[16];
    const float* beg1 = (const float*)d_in[17];
    const float* Wg2  = (const float*)d_in[18];
    const float* bg2  = (const float*)d_in[19];
    const float* gg2  = (const float*)d_in[20];
    const float* beg2 = (const float*)d_in[21];
    const float* Wn1  = (const float*)d_in[22];
    const float* bn1  = (const float*)d_in[23];
    const float* gn1  = (const float*)d_in[24];
    const float* ben1 = (const float*)d_in[25];
    const float* Wn2  = (const float*)d_in[26];
    const float* bn2  = (const float*)d_in[27];

    char* w = (char*)d_ws;
    float* sq     = (float*)wsAlloc(w, (size_t)NN * 4);
    int*   idx    = (int*)  wsAlloc(w, (size_t)NN * KK * 4);
    float* h0     = (float*)wsAlloc(w, (size_t)NN * 12 * 4);
    float* hA     = (float*)wsAlloc(w, (size_t)NN * 64 * 4);
    float* hB     = (float*)wsAlloc(w, (size_t)NN * 64 * 4);
    float* hg1    = (float*)wsAlloc(w, (size_t)NN * 128 * 4);
    float* ag2    = (float*)wsAlloc(w, (size_t)NN * 128 * 4);
    float* hg2    = (float*)wsAlloc(w, (size_t)NN * 512 * 4);   // 64 MiB; doubles as G during KNN
    float* ps     = (float*)wsAlloc(w, (size_t)(NN / 64) * 512 * 4);
    float* pss    = (float*)wsAlloc(w, (size_t)(NN / 64) * 512 * 4);
    float* bnA    = (float*)wsAlloc(w, 512 * 4);
    float* bnS    = (float*)wsAlloc(w, 512 * 4);
    float* pooled = (float*)wsAlloc(w, 16 * 512 * 4);
    float* t16    = (float*)wsAlloc(w, 16 * 512 * 4);

    // ---- local covariance features ----
    knn3v3_kernel<<<dim3(PP / 8, BB), 512, 0, stream>>>(x, idx);
    cov_kernel<<<NN / 256, 256, 0, stream>>>(x, idx, h0);

    // 64-tile dense (C=64 layers): R = NN/64 partial rows.
    auto dense = [&](const float* in, int K, int C, const float* Wp, const float* bp,
                     const float* gp, const float* bep,
                     const float* aInP, const float* bInP, float* out) {
        gemm_stats_kernel<<<dim3(C / 64, NN / 64), 256, 0, stream>>>(
            in, Wp, bp, out, aInP, bInP, ps, pss, K, C);
        bn_final2_kernel<<<C, 256, 0, stream>>>(ps, pss, gp, bep, bnA, bnS, C, NN / 64);
    };
    // 128-tile dense (C>=128 layers): R = NN/128 partial rows.
    auto dense128 = [&](const float* in, int K, int C, const float* Wp, const float* bp,
                        const float* gp, const float* bep, float* out) {
        gemm_stats128_kernel<<<dim3(C / 128, NN / 128), 256, 0, stream>>>(
            in, Wp, bp, out, ps, pss, K, C);
        bn_final2_kernel<<<C, 256, 0, stream>>>(ps, pss, gp, bep, bnA, bnS, C, NN / 128);
    };

    // point MLP: BN of layer n applied on the A-load of layer n+1 (single consumer)
    dense(h0, 12, 64, W1, b1, g1, be1, nullptr, nullptr, hA);   // hA = raw1; stats1
    dense(hA, 64, 64, W2, b2, g2, be2, bnA, bnS, hB);           // hB = raw2; stats2
    dense(hB, 64, 64, W3, b3, g3, be3, bnA, bnS, hA);           // hA = raw3; stats3
    bnsq_kernel<<<NN / 4, 256, 0, stream>>>(hA, bnA, bnS, sq, 64);   // BN+ReLU in place + sumsq

    // KNN in feature space: symmetric gram into hg2 (dead until the final dense).
    float* Gbuf = hg2;
    auto knn_feat = [&](const float* f, int D) {
        for (int b0 = 0; b0 < BB; b0 += 4) {
            gram128_sym_kernel<<<dim3(136, 4), 256, 0, stream>>>(f, Gbuf, D, b0);
            knn_sel3_kernel<<<dim3(PP / 4, 4), 256, 0, stream>>>(Gbuf, sq, idx, b0);
        }
    };

    // ---- graph layer 1 (64-d knn) ----
    knn_feat(hA, 64);
    gathermax4_kernel<<<(int)(((size_t)NN * 16) / 256), 256, 0, stream>>>(hA, idx, hB, 16);
    dense128(hB, 64, 128, Wg1, bg1, gg1, beg1, hg1);
    bnsq_kernel<<<NN / 4, 256, 0, stream>>>(hg1, bnA, bnS, sq, 128);  // BN+ReLU + sumsq

    // ---- graph layer 2 (128-d knn) ----
    knn_feat(hg1, 128);
    gathermax4_kernel<<<(int)(((size_t)NN * 32) / 256), 256, 0, stream>>>(hg1, idx, ag2, 32);
    dense128(ag2, 128, 512, Wg2, bg2, gg2, beg2, hg2);          // hg2 now real output

    // ---- global max pool (BN+ReLU fused) + bottleneck (two-stage K-split GEMMs) ----
    hipMemsetAsync(pooled, 0, 16 * 512 * 4, stream);
    segmax_bn_kernel<<<dim3(BB, 16), 256, 0, stream>>>(hg2, bnA, bnS, pooled);
    gemm16_part_kernel<<<dim3(8, 8), 256, 0, stream>>>(pooled, Wn1, ps);
    gemm16_reduce_kernel<<<32, 256, 0, stream>>>(ps, bn1, t16);
    bn16_kernel<<<2, 256, 0, stream>>>(t16, gn1, ben1);
    gemm16_part_kernel<<<dim3(8, 8), 256, 0, stream>>>(t16, Wn2, ps);
    gemm16_reduce_kernel<<<32, 256, 0, stream>>>(ps, bn2, (float*)d_out);
}

// Round 17
// 817.069 us; speedup vs baseline: 1.8466x; 1.0106x over previous
//
#include <hip/hip_runtime.h>

#define BB 16
#define PP 2048
#define NN 32768   // BB*PP
#define KK 16
#define EPSF 1e-5f

// ============================================================
// Wave-parallel top-16 selection (R12 known-good — FROZEN core).
// R13's deeper Q-caching spilled (360 MB scratch, 130us) -> this exact form
// (88us, ~4MB, VALUBusy 93%). Do not add live state to this loop without
// checking FETCH/WRITE_SIZE afterwards.
// R15 ledger: gather loads must NOT be fused into register-heavy GEMM bodies
// (acc spills at 64-VGPR cap; per-XCD L2 is only 4 MiB so >4MiB scatter
// working sets thrash to HBM). gathermax4 standalone is the known-good form.
// R17: gram now emits DISTANCES (sq_p + sq_q - 2*dot, +1e10 diag) so sel is
// a pure load+topk kernel (no ssq staging, no barrier, zero LDS).
// ============================================================
#define REP32(M) M(0) M(1) M(2) M(3) M(4) M(5) M(6) M(7) M(8) M(9) M(10) M(11) \
                 M(12) M(13) M(14) M(15) M(16) M(17) M(18) M(19) M(20) M(21) M(22) \
                 M(23) M(24) M(25) M(26) M(27) M(28) M(29) M(30) M(31)
#define DECLD(j) float D##j;

#define MPS(EO, FO, DA, JA, DB, JB) \
    { bool lt_ = (DB) < (DA); EO = lt_ ? (DB) : (DA); FO = lt_ ? (JB) : (JA); }

#define GTREE(GV, GS, dA,sA, dB,sB, dC,sC, dD,sD, dE,sE, dF,sF, dG,sG, dH,sH) { \
    float p0_, p1_, p2_, p3_, q0_, q1_; int o0_, o1_, o2_, o3_, r0_, r1_; \
    MPS(p0_, o0_, dA, sA, dB, sB) \
    MPS(p1_, o1_, dC, sC, dD, sD) \
    MPS(p2_, o2_, dE, sE, dF, sF) \
    MPS(p3_, o3_, dG, sG, dH, sH) \
    MPS(q0_, r0_, p0_, o0_, p1_, o1_) \
    MPS(q1_, r1_, p2_, o2_, p3_, o3_) \
    MPS(GV, GS, q0_, r0_, q1_, r1_) }

#define GT0 GTREE(G0v,H0v, D0,0,D1,1,D2,2,D3,3,D4,4,D5,5,D6,6,D7,7)
#define GT1 GTREE(G1v,H1v, D8,8,D9,9,D10,10,D11,11,D12,12,D13,13,D14,14,D15,15)
#define GT2 GTREE(G2v,H2v, D16,16,D17,17,D18,18,D19,19,D20,20,D21,21,D22,22,D23,23)
#define GT3 GTREE(G3v,H3v, D24,24,D25,25,D26,26,D27,27,D28,28,D29,29,D30,30,D31,31)

#define INVG0 \
    D0 = (wslot_ == 0) ? 3.4e38f : D0;  D1 = (wslot_ == 1) ? 3.4e38f : D1; \
    D2 = (wslot_ == 2) ? 3.4e38f : D2;  D3 = (wslot_ == 3) ? 3.4e38f : D3; \
    D4 = (wslot_ == 4) ? 3.4e38f : D4;  D5 = (wslot_ == 5) ? 3.4e38f : D5; \
    D6 = (wslot_ == 6) ? 3.4e38f : D6;  D7 = (wslot_ == 7) ? 3.4e38f : D7;
#define INVG1 \
    D8  = (wslot_ == 8)  ? 3.4e38f : D8;  D9  = (wslot_ == 9)  ? 3.4e38f : D9; \
    D10 = (wslot_ == 10) ? 3.4e38f : D10; D11 = (wslot_ == 11) ? 3.4e38f : D11; \
    D12 = (wslot_ == 12) ? 3.4e38f : D12; D13 = (wslot_ == 13) ? 3.4e38f : D13; \
    D14 = (wslot_ == 14) ? 3.4e38f : D14; D15 = (wslot_ == 15) ? 3.4e38f : D15;
#define INVG2 \
    D16 = (wslot_ == 16) ? 3.4e38f : D16; D17 = (wslot_ == 17) ? 3.4e38f : D17; \
    D18 = (wslot_ == 18) ? 3.4e38f : D18; D19 = (wslot_ == 19) ? 3.4e38f : D19; \
    D20 = (wslot_ == 20) ? 3.4e38f : D20; D21 = (wslot_ == 21) ? 3.4e38f : D21; \
    D22 = (wslot_ == 22) ? 3.4e38f : D22; D23 = (wslot_ == 23) ? 3.4e38f : D23;
#define INVG3 \
    D24 = (wslot_ == 24) ? 3.4e38f : D24; D25 = (wslot_ == 25) ? 3.4e38f : D25; \
    D26 = (wslot_ == 26) ? 3.4e38f : D26; D27 = (wslot_ == 27) ? 3.4e38f : D27; \
    D28 = (wslot_ == 28) ? 3.4e38f : D28; D29 = (wslot_ == 29) ? 3.4e38f : D29; \
    D30 = (wslot_ == 30) ? 3.4e38f : D30; D31 = (wslot_ == 31) ? 3.4e38f : D31;

#define TOPK16_BODY(OROW, BASE) { \
    float G0v, G1v, G2v, G3v; int H0v, H1v, H2v, H3v; \
    GT0 GT1 GT2 GT3 \
    int mykeep_ = 0; \
    for (int it_ = 0; it_ < KK; ++it_) { \
        float z_; int y_; \
        { float u0_, u1_; int v0_, v1_; \
          MPS(u0_, v0_, G0v, H0v, G1v, H1v) \
          MPS(u1_, v1_, G2v, H2v, G3v, H3v) \
          MPS(z_, y_, u0_, v0_, u1_, v1_) } \
        float v_ = z_; \
        _Pragma("unroll") \
        for (int off_ = 32; off_; off_ >>= 1) \
            v_ = fminf(v_, __shfl_xor(v_, off_)); \
        const int cil_ = ((y_ >> 2) << 8) + (y_ & 3) + (lane << 2); \
        unsigned long long mk_ = __ballot(z_ == v_); \
        int ci_; \
        if (__popcll(mk_) == 1) { \
            ci_ = __shfl(cil_, (int)(__ffsll((long long)mk_) - 1)); \
        } else { \
            ci_ = 0x7fffffff; \
            unsigned long long m2_ = mk_; \
            while (m2_) { \
                int l2_ = (int)(__ffsll((long long)m2_) - 1); \
                int c2_ = __shfl(cil_, l2_); \
                ci_ = c2_ < ci_ ? c2_ : ci_; \
                m2_ &= m2_ - 1; \
            } \
        } \
        const int wslot_ = ((ci_ >> 8) << 2) | (ci_ & 3); \
        if (lane == ((ci_ & 255) >> 2)) { \
            if (wslot_ < 8)       { INVG0 GT0 } \
            else if (wslot_ < 16) { INVG1 GT1 } \
            else if (wslot_ < 24) { INVG2 GT2 } \
            else                  { INVG3 GT3 } \
        } \
        mykeep_ = (lane == it_) ? ci_ : mykeep_; \
    } \
    if (lane < KK) (OROW)[lane] = (BASE) + mykeep_; \
}

// ============================ 3-D KNN (ONE query per wave, 8 waves/block) ============================
#define KNN3_CHUNK(jj, a0, a1, a2, a3) { \
    float4 cx = px4[jj * 64 + lane]; \
    float4 cy = py4[jj * 64 + lane]; \
    float4 cz = pz4[jj * 64 + lane]; \
    float4 cs = pq4[jj * 64 + lane]; \
    const int c0_ = jj * 256 + lane * 4; \
    D##a0 = sqQ + cs.x - 2.f * (qx * cx.x + qy * cy.x + qz * cz.x); if (c0_ + 0 == q) D##a0 += 1e10f; \
    D##a1 = sqQ + cs.y - 2.f * (qx * cx.y + qy * cy.y + qz * cz.y); if (c0_ + 1 == q) D##a1 += 1e10f; \
    D##a2 = sqQ + cs.z - 2.f * (qx * cx.z + qy * cy.z + qz * cz.z); if (c0_ + 2 == q) D##a2 += 1e10f; \
    D##a3 = sqQ + cs.w - 2.f * (qx * cx.w + qy * cy.w + qz * cz.w); if (c0_ + 3 == q) D##a3 += 1e10f; \
}

__global__ void __launch_bounds__(512, 8) knn3v3_kernel(const float* __restrict__ x,
                                                        int* __restrict__ idx) {
    __shared__ float spx[PP], spy[PP], spz[PP], ssq[PP];
    const int b = blockIdx.y, tid = threadIdx.x;
    const float* xc = x + (size_t)b * PP * 3;
    for (int i = tid; i < PP; i += 512) {
        float a = xc[i * 3 + 0], b2 = xc[i * 3 + 1], c2 = xc[i * 3 + 2];
        spx[i] = a; spy[i] = b2; spz[i] = c2;
        ssq[i] = a * a + b2 * b2 + c2 * c2;
    }
    __syncthreads();
    const int lane = tid & 63, wv = tid >> 6;
    const float4* px4 = (const float4*)spx;
    const float4* py4 = (const float4*)spy;
    const float4* pz4 = (const float4*)spz;
    const float4* pq4 = (const float4*)ssq;
    const int q = blockIdx.x * 8 + wv;
    const float qx = spx[q], qy = spy[q], qz = spz[q], sqQ = ssq[q];
    REP32(DECLD)
    KNN3_CHUNK(0, 0, 1, 2, 3)   KNN3_CHUNK(1, 4, 5, 6, 7)
    KNN3_CHUNK(2, 8, 9, 10, 11) KNN3_CHUNK(3, 12, 13, 14, 15)
    KNN3_CHUNK(4, 16, 17, 18, 19) KNN3_CHUNK(5, 20, 21, 22, 23)
    KNN3_CHUNK(6, 24, 25, 26, 27) KNN3_CHUNK(7, 28, 29, 30, 31)
    int* orow = idx + ((size_t)b * PP + q) * KK;
    TOPK16_BODY(orow, b * PP)
}

// ============================ local covariance -> h0[N,12] ============================
__global__ void cov_kernel(const float* __restrict__ x, const int* __restrict__ idx,
                           float* __restrict__ h0) {
    int p = blockIdx.x * 256 + threadIdx.x;
    if (p >= NN) return;
    const int* ip = idx + (size_t)p * KK;
    float nx[KK], ny[KK], nz[KK];
    float mx = 0.f, my = 0.f, mz = 0.f;
    #pragma unroll
    for (int k = 0; k < KK; ++k) {
        int j = ip[k];
        float a = x[j * 3 + 0], b2 = x[j * 3 + 1], c2 = x[j * 3 + 2];
        nx[k] = a; ny[k] = b2; nz[k] = c2;
        mx += a; my += b2; mz += c2;
    }
    mx *= (1.f / KK); my *= (1.f / KK); mz *= (1.f / KK);
    float cxx = 0, cxy = 0, cxz = 0, cyy = 0, cyz = 0, czz = 0;
    #pragma unroll
    for (int k = 0; k < KK; ++k) {
        float a = nx[k] - mx, b2 = ny[k] - my, c2 = nz[k] - mz;
        cxx += a * a;  cxy += a * b2;  cxz += a * c2;
        cyy += b2 * b2; cyz += b2 * c2; czz += c2 * c2;
    }
    const float s = 1.f / KK;
    float* o = h0 + (size_t)p * 12;
    o[0] = x[p * 3 + 0]; o[1] = x[p * 3 + 1]; o[2] = x[p * 3 + 2];
    o[3] = cxx * s; o[4]  = cxy * s; o[5]  = cxz * s;
    o[6] = cxy * s; o[7]  = cyy * s; o[8]  = cyz * s;
    o[9] = cxz * s; o[10] = cyz * s; o[11] = czz * s;
}

// ============ GEMM (64-tile) + fused BN-stats epilogue (+ optional BN-ReLU on A-load) ============
__global__ void gemm_stats_kernel(const float* __restrict__ A, const float* __restrict__ W,
                                  const float* __restrict__ bias, float* __restrict__ C,
                                  const float* __restrict__ aIn, const float* __restrict__ bIn,
                                  float* __restrict__ ps, float* __restrict__ pss,
                                  int K, int Nc) {
    __shared__ float As[16][68];
    __shared__ float Ws[16][68];
    const int tid = threadIdx.x;
    const int m0 = blockIdx.y * 64, n0 = blockIdx.x * 64;
    const int tx = tid & 15, ty = tid >> 4;
    float acc[4][4] = {};
    for (int k0 = 0; k0 < K; k0 += 16) {
        {
            int kk = tid & 15, mp0 = tid >> 4;
            bool kok = (k0 + kk < K);
            float ai = 1.f, bi = 0.f;
            if (aIn && kok) { ai = aIn[k0 + kk]; bi = bIn[k0 + kk]; }
            #pragma unroll
            for (int i = 0; i < 4; ++i) {
                int mp = mp0 + i * 16;
                float v = 0.f;
                if (kok) {
                    v = A[(size_t)(m0 + mp) * K + k0 + kk];
                    if (aIn) { v = fmaf(v, ai, bi); v = v > 0.f ? v : 0.f; }
                }
                As[kk][mp] = v;
            }
            int nn = tid & 63, kb = tid >> 6;
            #pragma unroll
            for (int i = 0; i < 4; ++i) {
                int kk3 = kb + i * 4;
                float v = 0.f;
                if (k0 + kk3 < K) v = W[(size_t)(k0 + kk3) * Nc + n0 + nn];
                Ws[kk3][nn] = v;
            }
        }
        __syncthreads();
        #pragma unroll
        for (int kk = 0; kk < 16; ++kk) {
            float4 a4 = *(const float4*)&As[kk][ty * 4];
            float4 b4 = *(const float4*)&Ws[kk][tx * 4];
            float av[4] = {a4.x, a4.y, a4.z, a4.w};
            float bv[4] = {b4.x, b4.y, b4.z, b4.w};
            #pragma unroll
            for (int i = 0; i < 4; ++i)
                #pragma unroll
                for (int j = 0; j < 4; ++j)
                    acc[i][j] = fmaf(av[i], bv[j], acc[i][j]);
        }
        __syncthreads();
    }
    float4 bb = *(const float4*)&bias[n0 + tx * 4];
    float bvv[4] = {bb.x, bb.y, bb.z, bb.w};
    float colS[4] = {}, colSS[4] = {};
    #pragma unroll
    for (int i = 0; i < 4; ++i) {
        int m = m0 + ty * 4 + i;
        float r[4];
        #pragma unroll
        for (int j = 0; j < 4; ++j) {
            r[j] = acc[i][j] + bvv[j];
            colS[j] += r[j];
            colSS[j] += r[j] * r[j];
        }
        float4 rr = {r[0], r[1], r[2], r[3]};
        *(float4*)&C[(size_t)m * Nc + n0 + tx * 4] = rr;
    }
    #pragma unroll
    for (int j = 0; j < 4; ++j) { As[ty][tx * 4 + j] = colS[j]; Ws[ty][tx * 4 + j] = colSS[j]; }
    __syncthreads();
    if (tid < 64) {
        float s = 0.f, ss = 0.f;
        #pragma unroll
        for (int t = 0; t < 16; ++t) { s += As[t][tid]; ss += Ws[t][tid]; }
        ps [(size_t)blockIdx.y * Nc + n0 + tid] = s;
        pss[(size_t)blockIdx.y * Nc + n0 + tid] = ss;
    }
}

// ============ GEMM (128-tile, 8x8 acc) + fused BN-stats epilogue ============
__global__ void gemm_stats128_kernel(const float* __restrict__ A, const float* __restrict__ W,
                                     const float* __restrict__ bias, float* __restrict__ C,
                                     float* __restrict__ ps, float* __restrict__ pss,
                                     int K, int Nc) {
    __shared__ float As[16][136];
    __shared__ float Ws[16][136];
    const int tid = threadIdx.x;
    const int m0 = blockIdx.y * 128, n0 = blockIdx.x * 128;
    const int tx = tid & 15, ty = tid >> 4;
    float acc[8][8] = {};
    for (int k0 = 0; k0 < K; k0 += 16) {
        {
            const int kk = tid & 15, r0 = tid >> 4;
            #pragma unroll
            for (int i = 0; i < 8; ++i) {
                int r = r0 + i * 16;
                As[kk][r] = A[(size_t)(m0 + r) * K + k0 + kk];
            }
            const int col = tid & 127, kb = tid >> 7;
            #pragma unroll
            for (int i = 0; i < 8; ++i) {
                int kk3 = kb + i * 2;
                Ws[kk3][col] = W[(size_t)(k0 + kk3) * Nc + n0 + col];
            }
        }
        __syncthreads();
        #pragma unroll
        for (int kk2 = 0; kk2 < 16; ++kk2) {
            float4 a0 = *(const float4*)&As[kk2][ty * 8];
            float4 a1 = *(const float4*)&As[kk2][ty * 8 + 4];
            float4 b0 = *(const float4*)&Ws[kk2][tx * 8];
            float4 b1 = *(const float4*)&Ws[kk2][tx * 8 + 4];
            float av[8] = {a0.x, a0.y, a0.z, a0.w, a1.x, a1.y, a1.z, a1.w};
            float bv[8] = {b0.x, b0.y, b0.z, b0.w, b1.x, b1.y, b1.z, b1.w};
            #pragma unroll
            for (int i = 0; i < 8; ++i)
                #pragma unroll
                for (int j = 0; j < 8; ++j)
                    acc[i][j] = fmaf(av[i], bv[j], acc[i][j]);
        }
        __syncthreads();
    }
    float4 bb0 = *(const float4*)&bias[n0 + tx * 8];
    float4 bb1 = *(const float4*)&bias[n0 + tx * 8 + 4];
    float bvv[8] = {bb0.x, bb0.y, bb0.z, bb0.w, bb1.x, bb1.y, bb1.z, bb1.w};
    float colS[8] = {}, colSS[8] = {};
    #pragma unroll
    for (int i = 0; i < 8; ++i) {
        int m = m0 + ty * 8 + i;
        float r[8];
        #pragma unroll
        for (int j = 0; j < 8; ++j) {
            r[j] = acc[i][j] + bvv[j];
            colS[j] += r[j];
            colSS[j] += r[j] * r[j];
        }
        float4 r0v = {r[0], r[1], r[2], r[3]};
        float4 r1v = {r[4], r[5], r[6], r[7]};
        float* row = &C[(size_t)m * Nc + n0 + tx * 8];
        *(float4*)row = r0v;
        *(float4*)(row + 4) = r1v;
    }
    #pragma unroll
    for (int j = 0; j < 8; ++j) { As[ty][tx * 8 + j] = colS[j]; Ws[ty][tx * 8 + j] = colSS[j]; }
    __syncthreads();
    if (tid < 128) {
        float s = 0.f, ss = 0.f;
        #pragma unroll
        for (int t = 0; t < 16; ++t) { s += As[t][tid]; ss += Ws[t][tid]; }
        ps [(size_t)blockIdx.y * Nc + n0 + tid] = s;
        pss[(size_t)blockIdx.y * Nc + n0 + tid] = ss;
    }
}

// ============ SYMMETRIC gram -> DISTANCES, 128x128 tiles, upper tri + mirror ============
// Writes d[p][q] = sq[p] + sq[q] - 2*dot (+1e10 on the diagonal), so sel is a
// pure load+topk. Mirror recomputes the same expression from acc (fp add is
// commutative -> bitwise identical to the normal write; matches old sel's
// "sqQ + s - 2g then +1e10" op order exactly).
__global__ void gram128_sym_kernel(const float* __restrict__ f, const float* __restrict__ sq,
                                   float* __restrict__ G, int D, int b0) {
    __shared__ float As[16][132];
    __shared__ float Bs[16][132];
    int t = blockIdx.x, ti = 0;
    while (t >= 16 - ti) { t -= 16 - ti; ++ti; }
    const int tj = ti + t;                    // ti <= tj
    const int pm0 = ti * 128, qn0 = tj * 128;
    const float* fc = f + (size_t)(b0 + blockIdx.y) * PP * D;
    const float* sqb = sq + (size_t)(b0 + blockIdx.y) * PP;
    float* Gb = G + (size_t)blockIdx.y * PP * PP;
    const int tid = threadIdx.x;
    const int tx = tid & 15, ty = tid >> 4;
    float acc[8][8] = {};
    for (int k0 = 0; k0 < D; k0 += 16) {
        const int kk = tid & 15, r0 = tid >> 4;
        #pragma unroll
        for (int i = 0; i < 8; ++i) {
            int r = r0 + i * 16;
            As[kk][r] = fc[(size_t)(pm0 + r) * D + k0 + kk];
            Bs[kk][r] = fc[(size_t)(qn0 + r) * D + k0 + kk];
        }
        __syncthreads();
        #pragma unroll
        for (int kk2 = 0; kk2 < 16; ++kk2) {
            float4 a0 = *(const float4*)&As[kk2][ty * 8];
            float4 a1 = *(const float4*)&As[kk2][ty * 8 + 4];
            float4 b0v = *(const float4*)&Bs[kk2][tx * 8];
            float4 b1v = *(const float4*)&Bs[kk2][tx * 8 + 4];
            float av[8] = {a0.x, a0.y, a0.z, a0.w, a1.x, a1.y, a1.z, a1.w};
            float bv[8] = {b0v.x, b0v.y, b0v.z, b0v.w, b1v.x, b1v.y, b1v.z, b1v.w};
            #pragma unroll
            for (int i = 0; i < 8; ++i)
                #pragma unroll
                for (int j = 0; j < 8; ++j)
                    acc[i][j] = fmaf(av[i], bv[j], acc[i][j]);
        }
        __syncthreads();
    }
    float sA[8], sB[8];
    #pragma unroll
    for (int i = 0; i < 8; ++i) sA[i] = sqb[pm0 + ty * 8 + i];
    #pragma unroll
    for (int j = 0; j < 8; ++j) sB[j] = sqb[qn0 + tx * 8 + j];
    #pragma unroll
    for (int i = 0; i < 8; ++i) {
        const int rp = pm0 + ty * 8 + i;
        float d[8];
        #pragma unroll
        for (int j = 0; j < 8; ++j) d[j] = sA[i] + sB[j] - 2.f * acc[i][j];
        if (ti == tj) {
            #pragma unroll
            for (int j = 0; j < 8; ++j)
                if (rp == qn0 + tx * 8 + j) d[j] += 1e10f;
        }
        float4 r0v = {d[0], d[1], d[2], d[3]};
        float4 r1v = {d[4], d[5], d[6], d[7]};
        float* row = Gb + (size_t)rp * PP + qn0 + tx * 8;
        *(float4*)row = r0v;
        *(float4*)(row + 4) = r1v;
    }
    if (ti != tj) {
        #pragma unroll
        for (int j = 0; j < 8; ++j) {
            float dm[8];
            #pragma unroll
            for (int i = 0; i < 8; ++i) dm[i] = sA[i] + sB[j] - 2.f * acc[i][j];
            float4 c0 = {dm[0], dm[1], dm[2], dm[3]};
            float4 c1 = {dm[4], dm[5], dm[6], dm[7]};
            float* row = Gb + (size_t)(qn0 + tx * 8 + j) * PP + pm0 + ty * 8;
            *(float4*)row = c0;
            *(float4*)(row + 4) = c1;
        }
    }
}

// ============ top-16 from precomputed distance rows (wave per query, zero LDS) ============
#define SEL_CHUNK(jj, a0, a1, a2, a3) { \
    float4 g4 = Gr[jj * 64 + lane]; \
    D##a0 = g4.x; D##a1 = g4.y; D##a2 = g4.z; D##a3 = g4.w; \
}

// 8 blocks/CU -> 32 waves/CU.
__global__ void __launch_bounds__(256, 8) knn_sel3_kernel(const float* __restrict__ G,
                                                          int* __restrict__ idx, int b0) {
    const int bg = blockIdx.y, b = b0 + bg, tid = threadIdx.x;
    const int lane = tid & 63, wv = tid >> 6;
    const int ql = blockIdx.x * 4 + wv;
    const float4* Gr = (const float4*)(G + ((size_t)bg * PP + ql) * PP);
    REP32(DECLD)
    SEL_CHUNK(0, 0, 1, 2, 3)   SEL_CHUNK(1, 4, 5, 6, 7)
    SEL_CHUNK(2, 8, 9, 10, 11) SEL_CHUNK(3, 12, 13, 14, 15)
    SEL_CHUNK(4, 16, 17, 18, 19) SEL_CHUNK(5, 20, 21, 22, 23)
    SEL_CHUNK(6, 24, 25, 26, 27) SEL_CHUNK(7, 28, 29, 30, 31)
    int* orow = idx + ((size_t)b * PP + ql) * KK;
    TOPK16_BODY(orow, b * PP)
}

// ============ fused BN-apply(+ReLU, in place) + row sum-of-squares ============
__global__ void bnsq_kernel(float* __restrict__ h, const float* __restrict__ a,
                            const float* __restrict__ bs, float* __restrict__ sq, int C) {
    const int lane = threadIdx.x & 63;
    const int row = blockIdx.x * 4 + (threadIdx.x >> 6);
    float* hr = h + (size_t)row * C;
    float s = 0.f;
    for (int d = lane; d < C; d += 64) {
        float v = fmaf(hr[d], a[d], bs[d]);
        v = v > 0.f ? v : 0.f;
        hr[d] = v;
        s += v * v;
    }
    #pragma unroll
    for (int off = 32; off; off >>= 1) s += __shfl_down(s, off);
    if (lane == 0) sq[row] = s;
}

// ============================ gather + max over K neighbors (float4 channels) ============================
__global__ void gathermax4_kernel(const float* __restrict__ f, const int* __restrict__ idx,
                                  float* __restrict__ agg, int C4) {
    size_t flat = (size_t)blockIdx.x * 256 + threadIdx.x;
    int c4 = (int)(flat % C4);
    int n = (int)(flat / C4);
    const int* ip = idx + (size_t)n * KK;
    const float4* f4 = (const float4*)f;
    float4 m = {-3.4e38f, -3.4e38f, -3.4e38f, -3.4e38f};
    #pragma unroll
    for (int k = 0; k < KK; ++k) {
        float4 v = f4[(size_t)ip[k] * C4 + c4];
        m.x = fmaxf(m.x, v.x); m.y = fmaxf(m.y, v.y);
        m.z = fmaxf(m.z, v.z); m.w = fmaxf(m.w, v.w);
    }
    ((float4*)agg)[flat] = m;
}

// ============ BN final reduce: one block per column over R partials ============
__global__ void bn_final2_kernel(const float* __restrict__ ps, const float* __restrict__ pss,
                                 const float* __restrict__ g, const float* __restrict__ be,
                                 float* __restrict__ a, float* __restrict__ bs,
                                 int C, int R) {
    const int c = blockIdx.x, tid = threadIdx.x;
    const int lane = tid & 63, wv = tid >> 6;
    __shared__ float sh_s[4], sh_ss[4];
    float s = 0.f, ss = 0.f;
    for (int r = tid; r < R; r += 256) {
        s  += ps [(size_t)r * C + c];
        ss += pss[(size_t)r * C + c];
    }
    #pragma unroll
    for (int off = 32; off; off >>= 1) {
        s  += __shfl_down(s, off);
        ss += __shfl_down(ss, off);
    }
    if (lane == 0) { sh_s[wv] = s; sh_ss[wv] = ss; }
    __syncthreads();
    if (tid == 0) {
        float ts = sh_s[0] + sh_s[1] + sh_s[2] + sh_s[3];
        float tss = sh_ss[0] + sh_ss[1] + sh_ss[2] + sh_ss[3];
        float m = ts / (float)NN;
        float v = tss / (float)NN - m * m;
        float rstd = rsqrtf(v + EPSF);
        float aa = rstd * g[c];
        a[c] = aa;
        bs[c] = be[c] - m * aa;
    }
}

// ============================ segment max pool with fused BN+ReLU ============================
__global__ void segmax_bn_kernel(const float* __restrict__ h, const float* __restrict__ a,
                                 const float* __restrict__ bs, float* __restrict__ pooled) {
    const int b = blockIdx.x, chunk = blockIdx.y, tid = threadIdx.x;
    const int r0 = chunk * 128;
    for (int cb = 0; cb < 512; cb += 256) {
        int c = cb + tid;
        float aa = a[c], bb2 = bs[c];
        float m = 0.f;   // relu'd values >= 0
        for (int r = r0; r < r0 + 128; ++r) {
            float v = fmaf(h[((size_t)b * PP + r) * 512 + c], aa, bb2);
            v = v > 0.f ? v : 0.f;
            m = fmaxf(m, v);
        }
        atomicMax((int*)&pooled[b * 512 + c], __float_as_int(m));
    }
}

// ============ bottleneck GEMM (M=16, K=512, Nc=512): K-split two-stage ============
__global__ void gemm16_part_kernel(const float* __restrict__ A, const float* __restrict__ W,
                                   float* __restrict__ part) {
    __shared__ float As[16][68];
    const int tid = threadIdx.x;
    const int n0 = blockIdx.x * 64, k0 = blockIdx.y * 64;
    for (int i = tid; i < 16 * 64; i += 256) {
        int row = i >> 6, kk = i & 63;
        As[row][kk] = A[(size_t)row * 512 + k0 + kk];
    }
    __syncthreads();
    const int col = n0 + (tid & 63);
    const int rg = (tid >> 6) * 4;
    float a0 = 0.f, a1 = 0.f, a2 = 0.f, a3 = 0.f;
    #pragma unroll 8
    for (int kk = 0; kk < 64; ++kk) {
        float w = W[(size_t)(k0 + kk) * 512 + col];
        a0 = fmaf(As[rg + 0][kk], w, a0);
        a1 = fmaf(As[rg + 1][kk], w, a1);
        a2 = fmaf(As[rg + 2][kk], w, a2);
        a3 = fmaf(As[rg + 3][kk], w, a3);
    }
    float* p = part + (size_t)blockIdx.y * 16 * 512;
    p[(size_t)(rg + 0) * 512 + col] = a0;
    p[(size_t)(rg + 1) * 512 + col] = a1;
    p[(size_t)(rg + 2) * 512 + col] = a2;
    p[(size_t)(rg + 3) * 512 + col] = a3;
}

__global__ void gemm16_reduce_kernel(const float* __restrict__ part,
                                     const float* __restrict__ bias,
                                     float* __restrict__ C) {
    int i = blockIdx.x * 256 + threadIdx.x;    // 8192 outputs
    int col = i & 511, row = i >> 9;
    float s = bias[col];
    #pragma unroll
    for (int ks = 0; ks < 8; ++ks)
        s += part[((size_t)ks * 16 + row) * 512 + col];
    C[i] = s;
}

// ============================ BN over 16 rows + ReLU (in place) ============================
__global__ void bn16_kernel(float* __restrict__ h, const float* __restrict__ g,
                            const float* __restrict__ be) {
    int c = blockIdx.x * 256 + threadIdx.x;
    if (c >= 512) return;
    float s = 0.f, ss = 0.f;
    for (int r = 0; r < 16; ++r) { float v = h[r * 512 + c]; s += v; ss += v * v; }
    float m = s / 16.f;
    float var = ss / 16.f - m * m;
    float rstd = rsqrtf(var + EPSF);
    float aa = rstd * g[c], bb = be[c] - m * aa;
    for (int r = 0; r < 16; ++r) {
        float v = h[r * 512 + c] * aa + bb;
        h[r * 512 + c] = v > 0.f ? v : 0.f;
    }
}

// ============================ host ============================
static inline void* wsAlloc(char*& w, size_t bytes) {
    void* p = (void*)w;
    w += (bytes + 255) & ~(size_t)255;
    return p;
}

extern "C" void kernel_launch(void* const* d_in, const int* in_sizes, int n_in,
                              void* d_out, int out_size, void* d_ws, size_t ws_size,
                              hipStream_t stream) {
    (void)in_sizes; (void)n_in; (void)out_size; (void)ws_size;
    const float* x    = (const float*)d_in[0];
    const float* W1   = (const float*)d_in[2];
    const float* b1   = (const float*)d_in[3];
    const float* g1   = (const float*)d_in[4];
    const float* be1  = (const float*)d_in[5];
    const float* W2   = (const float*)d_in[6];
    const float* b2   = (const float*)d_in[7];
    const float* g2   = (const float*)d_in[8];
    const float* be2  = (const float*)d_in[9];
    const float* W3   = (const float*)d_in[10];
    const float* b3   = (const float*)d_in[11];
    const float* g3   = (const float*)d_in[12];
    const float* be3  = (const float*)d_in[13];
    const float* Wg1  = (const float*)d_in[14];
    const float* bg1  = (const float*)d_in[15];
    const float* gg1  = (const float*)d_in[16];
    const float* beg1 = (const float*)d_in[17];
    const float* Wg2  = (const float*)d_in[18];
    const float* bg2  = (const float*)d_in[19];
    const float* gg2  = (const float*)d_in[20];
    const float* beg2 = (const float*)d_in[21];
    const float* Wn1  = (const float*)d_in[22];
    const float* bn1  = (const float*)d_in[23];
    const float* gn1  = (const float*)d_in[24];
    const float* ben1 = (const float*)d_in[25];
    const float* Wn2  = (const float*)d_in[26];
    const float* bn2  = (const float*)d_in[27];

    char* w = (char*)d_ws;
    float* sq     = (float*)wsAlloc(w, (size_t)NN * 4);
    int*   idx    = (int*)  wsAlloc(w, (size_t)NN * KK * 4);
    float* h0     = (float*)wsAlloc(w, (size_t)NN * 12 * 4);
    float* hA     = (float*)wsAlloc(w, (size_t)NN * 64 * 4);
    float* hB     = (float*)wsAlloc(w, (size_t)NN * 64 * 4);
    float* hg1    = (float*)wsAlloc(w, (size_t)NN * 128 * 4);
    float* ag2    = (float*)wsAlloc(w, (size_t)NN * 128 * 4);
    float* hg2    = (float*)wsAlloc(w, (size_t)NN * 512 * 4);   // 64 MiB; doubles as G during KNN
    float* ps     = (float*)wsAlloc(w, (size_t)(NN / 64) * 512 * 4);
    float* pss    = (float*)wsAlloc(w, (size_t)(NN / 64) * 512 * 4);
    float* bnA    = (float*)wsAlloc(w, 512 * 4);
    float* bnS    = (float*)wsAlloc(w, 512 * 4);
    float* pooled = (float*)wsAlloc(w, 16 * 512 * 4);
    float* t16    = (float*)wsAlloc(w, 16 * 512 * 4);

    // ---- local covariance features ----
    knn3v3_kernel<<<dim3(PP / 8, BB), 512, 0, stream>>>(x, idx);
    cov_kernel<<<NN / 256, 256, 0, stream>>>(x, idx, h0);

    // 64-tile dense (C=64 layers): R = NN/64 partial rows.
    auto dense = [&](const float* in, int K, int C, const float* Wp, const float* bp,
                     const float* gp, const float* bep,
                     const float* aInP, const float* bInP, float* out) {
        gemm_stats_kernel<<<dim3(C / 64, NN / 64), 256, 0, stream>>>(
            in, Wp, bp, out, aInP, bInP, ps, pss, K, C);
        bn_final2_kernel<<<C, 256, 0, stream>>>(ps, pss, gp, bep, bnA, bnS, C, NN / 64);
    };
    // 128-tile dense (C>=128 layers): R = NN/128 partial rows.
    auto dense128 = [&](const float* in, int K, int C, const float* Wp, const float* bp,
                        const float* gp, const float* bep, float* out) {
        gemm_stats128_kernel<<<dim3(C / 128, NN / 128), 256, 0, stream>>>(
            in, Wp, bp, out, ps, pss, K, C);
        bn_final2_kernel<<<C, 256, 0, stream>>>(ps, pss, gp, bep, bnA, bnS, C, NN / 128);
    };

    // point MLP: BN of layer n applied on the A-load of layer n+1 (single consumer)
    dense(h0, 12, 64, W1, b1, g1, be1, nullptr, nullptr, hA);   // hA = raw1; stats1
    dense(hA, 64, 64, W2, b2, g2, be2, bnA, bnS, hB);           // hB = raw2; stats2
    dense(hB, 64, 64, W3, b3, g3, be3, bnA, bnS, hA);           // hA = raw3; stats3
    bnsq_kernel<<<NN / 4, 256, 0, stream>>>(hA, bnA, bnS, sq, 64);   // BN+ReLU in place + sumsq

    // KNN in feature space: symmetric gram (-> distances) into hg2 (dead until final dense).
    float* Gbuf = hg2;
    auto knn_feat = [&](const float* f, int D) {
        for (int b0 = 0; b0 < BB; b0 += 4) {
            gram128_sym_kernel<<<dim3(136, 4), 256, 0, stream>>>(f, sq, Gbuf, D, b0);
            knn_sel3_kernel<<<dim3(PP / 4, 4), 256, 0, stream>>>(Gbuf, idx, b0);
        }
    };

    // ---- graph layer 1 (64-d knn) ----
    knn_feat(hA, 64);
    gathermax4_kernel<<<(int)(((size_t)NN * 16) / 256), 256, 0, stream>>>(hA, idx, hB, 16);
    dense128(hB, 64, 128, Wg1, bg1, gg1, beg1, hg1);
    bnsq_kernel<<<NN / 4, 256, 0, stream>>>(hg1, bnA, bnS, sq, 128);  // BN+ReLU + sumsq

    // ---- graph layer 2 (128-d knn) ----
    knn_feat(hg1, 128);
    gathermax4_kernel<<<(int)(((size_t)NN * 32) / 256), 256, 0, stream>>>(hg1, idx, ag2, 32);
    dense128(ag2, 128, 512, Wg2, bg2, gg2, beg2, hg2);          // hg2 now real output

    // ---- global max pool (BN+ReLU fused) + bottleneck (two-stage K-split GEMMs) ----
    hipMemsetAsync(pooled, 0, 16 * 512 * 4, stream);
    segmax_bn_kernel<<<dim3(BB, 16), 256, 0, stream>>>(hg2, bnA, bnS, pooled);
    gemm16_part_kernel<<<dim3(8, 8), 256, 0, stream>>>(pooled, Wn1, ps);
    gemm16_reduce_kernel<<<32, 256, 0, stream>>>(ps, bn1, t16);
    bn16_kernel<<<2, 256, 0, stream>>>(t16, gn1, ben1);
    gemm16_part_kernel<<<dim3(8, 8), 256, 0, stream>>>(t16, Wn2, ps);
    gemm16_reduce_kernel<<<32, 256, 0, stream>>>(ps, bn2, (float*)d_out);
}